// Round 1
// 837.401 us; speedup vs baseline: 1.0827x; 1.0827x over previous
//
#include <hip/hip_runtime.h>
#include <math.h>

#define Bq 256
#define Kn 64
#define Dd 2048
#define Nn 50000
#define Cc 5000
#define NHID 512
#define H2d 256
#define LDH 264   // padded LDS row stride (shorts) for gram staging
#define MP 5376   // padded P-matrix rows: 5000 cn + 120 pad + 256 pivots
#define PIVROW 5120

typedef __attribute__((ext_vector_type(8))) __bf16 bf16x8;
typedef __attribute__((ext_vector_type(4))) float f32x4;

__device__ __forceinline__ unsigned short f2bf(float f) {
    union { float f; unsigned int u; } v;
    v.f = f;
    unsigned int u = v.u;
    unsigned int r = (u + 0x7fff + ((u >> 16) & 1)) >> 16;   // RNE
    return (unsigned short)r;
}
__device__ __forceinline__ float bf2f(unsigned short h) {
    union { unsigned int u; float f; } v;
    v.u = ((unsigned int)h) << 16;
    return v.f;
}

// ---------------- small utility kernels ----------------

__global__ void k_zero_int(int* __restrict__ p, int n) {
    int i = blockIdx.x * 256 + threadIdx.x;
    if (i < n) p[i] = 0;
}

__global__ void k_count(const int* __restrict__ labels, int* __restrict__ cnt, int n) {
    int i = blockIdx.x * 256 + threadIdx.x;
    if (i < n) atomicAdd(&cnt[labels[i]], 1);
}

__global__ __launch_bounds__(1024) void k_scan(const int* __restrict__ cnt,
                                               int* __restrict__ off,
                                               int* __restrict__ pos, int C) {
    __shared__ int s[1024];
    __shared__ int carry;
    int tid = threadIdx.x;
    if (tid == 0) carry = 0;
    __syncthreads();
    for (int base = 0; base < C; base += 1024) {
        int i = base + tid;
        int v = (i < C) ? cnt[i] : 0;
        s[tid] = v;
        __syncthreads();
        for (int o = 1; o < 1024; o <<= 1) {
            int t = (tid >= o) ? s[tid - o] : 0;
            __syncthreads();
            s[tid] += t;
            __syncthreads();
        }
        int excl = carry + s[tid] - v;
        if (i < C) { off[i] = excl; pos[i] = excl; }
        __syncthreads();
        if (tid == 0) carry += s[1023];
        __syncthreads();
    }
}

__global__ void k_scatter(const int* __restrict__ labels, int* __restrict__ pos,
                          int* __restrict__ rowidx, int n) {
    int i = blockIdx.x * 256 + threadIdx.x;
    if (i < n) {
        int p = atomicAdd(&pos[labels[i]], 1);
        rowidx[p] = i;
    }
}

// ---------------- cluster mean + simm + normalized-mean (bf16) ----------------
__global__ __launch_bounds__(256) void k_meansimm(
    const float* __restrict__ feat, const int* __restrict__ rowidx,
    const int* __restrict__ off, const int* __restrict__ cnt,
    float* __restrict__ clu_mean, float* __restrict__ simm,
    unsigned short* __restrict__ cn) {
    int c = blockIdx.x;
    int t = threadIdx.x;
    int n = cnt[c], st = off[c];
    float4 a0 = {0.f, 0.f, 0.f, 0.f}, a1 = {0.f, 0.f, 0.f, 0.f};
    for (int r = 0; r < n; r++) {
        const float* row = feat + (size_t)rowidx[st + r] * Dd;
        float4 v0 = *(const float4*)(row + t * 4);
        float4 v1 = *(const float4*)(row + 1024 + t * 4);
        a0.x += v0.x; a0.y += v0.y; a0.z += v0.z; a0.w += v0.w;
        a1.x += v1.x; a1.y += v1.y; a1.z += v1.z; a1.w += v1.w;
    }
    float sc = 1.f / (float)(n > 1 ? n : 1);
    a0.x *= sc; a0.y *= sc; a0.z *= sc; a0.w *= sc;
    a1.x *= sc; a1.y *= sc; a1.z *= sc; a1.w *= sc;
    float* outr = clu_mean + (size_t)c * Dd;
    *(float4*)(outr + t * 4) = a0;
    *(float4*)(outr + 1024 + t * 4) = a1;
    float ss = a0.x * a0.x + a0.y * a0.y + a0.z * a0.z + a0.w * a0.w +
               a1.x * a1.x + a1.y * a1.y + a1.z * a1.z + a1.w * a1.w;
    __shared__ float red[256];
    red[t] = ss;
    __syncthreads();
    for (int s2 = 128; s2 > 0; s2 >>= 1) {
        if (t < s2) red[t] += red[t + s2];
        __syncthreads();
    }
    if (t == 0) simm[c] = red[0];
    float tot = red[0];
    float rnn = (tot > 0.f) ? rsqrtf(tot) : 0.f;
    ushort4 c0, c1;
    c0.x = f2bf(a0.x * rnn); c0.y = f2bf(a0.y * rnn);
    c0.z = f2bf(a0.z * rnn); c0.w = f2bf(a0.w * rnn);
    c1.x = f2bf(a1.x * rnn); c1.y = f2bf(a1.y * rnn);
    c1.z = f2bf(a1.z * rnn); c1.w = f2bf(a1.w * rnn);
    unsigned short* cr = cn + (size_t)c * Dd;
    *(ushort4*)(cr + t * 4) = c0;
    *(ushort4*)(cr + 1024 + t * 4) = c1;
}

// ---------------- normalized pivot rows -> PA[PIVROW+b] (bf16) ----------------
__global__ __launch_bounds__(256) void k_pivots(
    const float* __restrict__ feat, const int* __restrict__ indexes,
    unsigned short* __restrict__ PA) {
    int b = blockIdx.x, t = threadIdx.x;
    const float* row = feat + (size_t)indexes[b] * Dd;
    float4 v0 = *(const float4*)(row + t * 4);
    float4 v1 = *(const float4*)(row + 1024 + t * 4);
    float ss = v0.x * v0.x + v0.y * v0.y + v0.z * v0.z + v0.w * v0.w +
               v1.x * v1.x + v1.y * v1.y + v1.z * v1.z + v1.w * v1.w;
    __shared__ float red[256];
    red[t] = ss;
    __syncthreads();
    for (int s2 = 128; s2 > 0; s2 >>= 1) {
        if (t < s2) red[t] += red[t + s2];
        __syncthreads();
    }
    float tot = red[0];
    float rnn = (tot > 0.f) ? rsqrtf(tot) : 0.f;
    ushort4 c0, c1;
    c0.x = f2bf(v0.x * rnn); c0.y = f2bf(v0.y * rnn);
    c0.z = f2bf(v0.z * rnn); c0.w = f2bf(v0.w * rnn);
    c1.x = f2bf(v1.x * rnn); c1.y = f2bf(v1.y * rnn);
    c1.z = f2bf(v1.z * rnn); c1.w = f2bf(v1.w * rnn);
    unsigned short* cr = PA + (size_t)(PIVROW + b) * Dd;
    *(ushort4*)(cr + t * 4) = c0;
    *(ushort4*)(cr + 1024 + t * 4) = c1;
}

// ---------------- per-batch: A (MFMA hi/lo gram) only ----------------
__global__ __launch_bounds__(256) void k_build_ax(
    const float* __restrict__ feat, const float* __restrict__ clu_mean,
    const int* __restrict__ labels, const int* __restrict__ indexes,
    const int* __restrict__ knn, const float* __restrict__ all_pred,
    float* __restrict__ Abuf) {
    __shared__ unsigned short Hs[64 * LDH];   // hi bf16, padded rows (33 KB)
    __shared__ unsigned short Ls[64 * LDH];   // lo bf16 (33 KB)
    __shared__ float Gs[64 * 65];
    __shared__ const float* rowp[64];
    __shared__ float wj64[64];

    int b = blockIdx.x, tid = threadIdx.x;
    int wave = tid >> 6, lane = tid & 63, quad = lane >> 4, l16 = lane & 15;

    if (tid < 64) {
        const float* p = (tid == 0) ? feat + (size_t)indexes[b] * Dd
                                    : clu_mean + (size_t)labels[knn[b * 64 + tid]] * Dd;
        rowp[tid] = p;
        wj64[tid] = expf(all_pred[(b * 64 + tid) * 2 + 1]);
    }
    __syncthreads();

    // G = F F^T via 3-pass hi/lo bf16 MFMA, fp32 accumulate.
    f32x4 acc[4];
#pragma unroll
    for (int j = 0; j < 4; j++) acc[j] = (f32x4){0.f, 0.f, 0.f, 0.f};

    for (int ch = 0; ch < 8; ch++) {
        int d0 = ch * 256;
        __syncthreads();   // protect Hs/Ls from previous chunk's readers
#pragma unroll
        for (int q = 0; q < 16; q++) {
            int e4 = tid + q * 256;
            int row = e4 >> 6;
            int c4 = (e4 & 63) * 4;
            float4 v = *(const float4*)(rowp[row] + d0 + c4);
            ushort4 h, l;
            h.x = f2bf(v.x); l.x = f2bf(v.x - bf2f(h.x));
            h.y = f2bf(v.y); l.y = f2bf(v.y - bf2f(h.y));
            h.z = f2bf(v.z); l.z = f2bf(v.z - bf2f(h.z));
            h.w = f2bf(v.w); l.w = f2bf(v.w - bf2f(h.w));
            *(ushort4*)&Hs[row * LDH + c4] = h;
            *(ushort4*)&Ls[row * LDH + c4] = l;
        }
        __syncthreads();
#pragma unroll
        for (int ks = 0; ks < 8; ks++) {
            int kk = ks * 32 + quad * 8;
            bf16x8 ah = *(const bf16x8*)&Hs[(wave * 16 + l16) * LDH + kk];
            bf16x8 al = *(const bf16x8*)&Ls[(wave * 16 + l16) * LDH + kk];
#pragma unroll
            for (int j = 0; j < 4; j++) {
                bf16x8 bh = *(const bf16x8*)&Hs[(j * 16 + l16) * LDH + kk];
                bf16x8 bl = *(const bf16x8*)&Ls[(j * 16 + l16) * LDH + kk];
                acc[j] = __builtin_amdgcn_mfma_f32_16x16x32_bf16(ah, bh, acc[j], 0, 0, 0);
                acc[j] = __builtin_amdgcn_mfma_f32_16x16x32_bf16(ah, bl, acc[j], 0, 0, 0);
                acc[j] = __builtin_amdgcn_mfma_f32_16x16x32_bf16(al, bh, acc[j], 0, 0, 0);
            }
        }
    }
    __syncthreads();
    // C/D layout: col = l16, row = quad*4 + r
#pragma unroll
    for (int j = 0; j < 4; j++)
#pragma unroll
        for (int r = 0; r < 4; r++)
            Gs[(wave * 16 + quad * 4 + r) * 65 + j * 16 + l16] = acc[j][r];
    __syncthreads();
    // row softmax (thread r handles row r)
    if (tid < 64) {
        int r = tid;
        float mx = -1e30f;
        for (int c = 0; c < 64; c++) {
            float v = Gs[r * 65 + c] * wj64[c];
            mx = fmaxf(mx, v);
        }
        float s = 0.f;
        for (int c = 0; c < 64; c++) {
            float e = expf(Gs[r * 65 + c] * wj64[c] - mx);
            Gs[r * 65 + c] = e;
            s += e;
        }
        float inv = 1.f / s;
        float* Arow = Abuf + ((size_t)b * 64 + r) * 64;
        for (int c = 0; c < 64; c++) Arow[c] = Gs[r * 65 + c] * inv;
    }
}

// ---------------- weight repack: f32 [rows,Nhalf] -> Bp[k/8][Ntot][8] bf16 ----------------
template <int SPLIT>
__global__ __launch_bounds__(256) void k_pack_w(const float* __restrict__ W,
                                                unsigned short* __restrict__ Bp,
                                                int K, int Nhalf) {
    int Ntot = SPLIT ? 2 * Nhalf : Nhalf;
    int idx = blockIdx.x * 256 + threadIdx.x;
    int kb = idx / Ntot;
    int n = idx - kb * Ntot;
    ushort4 lo, hi;
    float v[8];
#pragma unroll
    for (int j = 0; j < 8; j++) {
        int k = kb * 8 + j;
        if (SPLIT)
            v[j] = (n < Nhalf) ? W[(size_t)k * Nhalf + n]
                               : W[(size_t)(K + k) * Nhalf + (n - Nhalf)];
        else
            v[j] = W[(size_t)k * Nhalf + n];
    }
    lo.x = f2bf(v[0]); lo.y = f2bf(v[1]); lo.z = f2bf(v[2]); lo.w = f2bf(v[3]);
    hi.x = f2bf(v[4]); hi.y = f2bf(v[5]); hi.z = f2bf(v[6]); hi.w = f2bf(v[7]);
    *(ushort4*)&Bp[(size_t)idx * 8] = lo;
    *(ushort4*)&Bp[(size_t)idx * 8 + 4] = hi;
}

// ---------------- bf16 MFMA GEMM (m97 structure) ----------------
template <int EPI>
__global__ __launch_bounds__(256) void gemm_bf16_mfma(
    const unsigned short* __restrict__ A, const unsigned short* __restrict__ Bp,
    float* __restrict__ C, int M, int K, int N,
    const float* __restrict__ bias, const float* __restrict__ pre_a) {
    __shared__ unsigned short Asm[128 * 32];
    __shared__ unsigned short Bsm[4 * 128 * 8];
    int tid = threadIdx.x;
    int wave = tid >> 6, lane = tid & 63;
    int quad = lane >> 4, l16 = lane & 15;
    int m0 = blockIdx.y * 128, n0 = blockIdx.x * 128;
    int wm = (wave >> 1) * 64, wn = (wave & 1) * 64;

    f32x4 acc[4][4];
#pragma unroll
    for (int i = 0; i < 4; i++)
#pragma unroll
        for (int j = 0; j < 4; j++) acc[i][j] = (f32x4){0.f, 0.f, 0.f, 0.f};

    int ia0 = wave * 2, ia1 = wave * 2 + 1;
    const unsigned short* gA0 = A + (size_t)(m0 + ia0 * 16 + (lane >> 2)) * K + (lane & 3) * 8;
    const unsigned short* gA1 = gA0 + (size_t)16 * K;
    const unsigned short* gB0 = Bp + (size_t)(n0 + lane) * 8 + (size_t)wave * N * 8;

    for (int k0 = 0; k0 < K; k0 += 32) {
        __syncthreads();
        size_t bko = (size_t)(k0 >> 3) * N * 8;
        __builtin_amdgcn_global_load_lds(
            (const __attribute__((address_space(1))) void*)(gA0 + k0),
            (__attribute__((address_space(3))) void*)(Asm + ia0 * 512), 16, 0, 0);
        __builtin_amdgcn_global_load_lds(
            (const __attribute__((address_space(1))) void*)(gA1 + k0),
            (__attribute__((address_space(3))) void*)(Asm + ia1 * 512), 16, 0, 0);
        __builtin_amdgcn_global_load_lds(
            (const __attribute__((address_space(1))) void*)(gB0 + bko),
            (__attribute__((address_space(3))) void*)(Bsm + wave * 1024), 16, 0, 0);
        __builtin_amdgcn_global_load_lds(
            (const __attribute__((address_space(1))) void*)(gB0 + bko + 512),
            (__attribute__((address_space(3))) void*)(Bsm + wave * 1024 + 512), 16, 0, 0);
        __syncthreads();

        bf16x8 a[4], b[4];
#pragma unroll
        for (int i = 0; i < 4; i++)
            a[i] = *(const bf16x8*)&Asm[(wm + i * 16 + l16) * 32 + quad * 8];
#pragma unroll
        for (int j = 0; j < 4; j++)
            b[j] = *(const bf16x8*)&Bsm[quad * 1024 + (wn + j * 16 + l16) * 8];
#pragma unroll
        for (int i = 0; i < 4; i++)
#pragma unroll
            for (int j = 0; j < 4; j++)
                acc[i][j] = __builtin_amdgcn_mfma_f32_16x16x32_bf16(
                    a[i], b[j], acc[i][j], 0, 0, 0);
    }

#pragma unroll
    for (int i = 0; i < 4; i++) {
#pragma unroll
        for (int j = 0; j < 4; j++) {
            int col = n0 + wn + j * 16 + l16;
            float bcol = (EPI == 1) ? bias[col] : 0.f;
            float acol = (EPI == 1) ? pre_a[col] : 0.f;
#pragma unroll
            for (int r = 0; r < 4; r++) {
                int row = m0 + wm + i * 16 + quad * 4 + r;
                float v = acc[i][j][r];
                if (EPI == 1) {
                    v += bcol;
                    v = (v >= 0.f) ? v : acol * v;
                }
                C[(size_t)row * N + col] = v;
            }
        }
    }
}

// ---------------- layer-1 mixing with P/Q gather:
// U[b,k,:] = P[rowid[k],:] - Q[b,:]; out = relu(Ua + A@Ub + bias) -> bf16
__global__ __launch_bounds__(256) void k_layer_agg1(
    const float* __restrict__ P, const float* __restrict__ Abuf,
    const int* __restrict__ labels, const int* __restrict__ knn,
    const float* __restrict__ bias, unsigned short* __restrict__ outp) {
    int b = blockIdx.x;
    int tid = threadIdx.x;
    __shared__ float Ast[64 * 68];
    __shared__ float Us[64 * 68];
    __shared__ int rowid[64];
    int ty = tid >> 4, tx = tid & 15;
    if (tid < 64)
        rowid[tid] = (tid == 0) ? (PIVROW + b) : labels[knn[b * 64 + tid]];
    const float* Ab = Abuf + (size_t)b * 64 * 64;
    for (int e4 = tid; e4 < 1024; e4 += 256) {
        float4 v = *(const float4*)(Ab + e4 * 4);
        int row = e4 >> 4;
        int c4 = (e4 & 15) * 4;
        Ast[(c4 + 0) * 68 + row] = v.x;
        Ast[(c4 + 1) * 68 + row] = v.y;
        Ast[(c4 + 2) * 68 + row] = v.z;
        Ast[(c4 + 3) * 68 + row] = v.w;
    }
    const float* Q = P + (size_t)(PIVROW + b) * 1024;
    for (int n0 = 0; n0 < NHID; n0 += 64) {
        __syncthreads();
#pragma unroll
        for (int kq = 0; kq < 4; kq++) {
            int e4 = tid + kq * 256;
            int row = e4 >> 4;
            int c4 = (e4 & 15) * 4;
            float4 v = *(const float4*)(P + (size_t)rowid[row] * 1024 + NHID + n0 + c4);
            float4 q = *(const float4*)(Q + NHID + n0 + c4);
            v.x -= q.x; v.y -= q.y; v.z -= q.z; v.w -= q.w;
            *(float4*)&Us[row * 68 + c4] = v;
        }
        __syncthreads();
        float acc[4][4];
#pragma unroll
        for (int i = 0; i < 4; i++)
#pragma unroll
            for (int j = 0; j < 4; j++) acc[i][j] = 0.f;
        for (int kk = 0; kk < 64; kk++) {
            float4 a4 = *(const float4*)&Ast[kk * 68 + ty * 4];
            float4 b4 = *(const float4*)&Us[kk * 68 + tx * 4];
            float aa[4] = {a4.x, a4.y, a4.z, a4.w};
            float bb[4] = {b4.x, b4.y, b4.z, b4.w};
#pragma unroll
            for (int i = 0; i < 4; i++)
#pragma unroll
                for (int j = 0; j < 4; j++) acc[i][j] += aa[i] * bb[j];
        }
#pragma unroll
        for (int i = 0; i < 4; i++) {
            int krow = ty * 4 + i;
            int m = b * 64 + krow;
            int n = n0 + tx * 4;
            float4 ua = *(const float4*)(P + (size_t)rowid[krow] * 1024 + n);
            float4 qa = *(const float4*)(Q + n);
            float v0 = fmaxf(ua.x - qa.x + acc[i][0] + bias[n + 0], 0.f);
            float v1 = fmaxf(ua.y - qa.y + acc[i][1] + bias[n + 1], 0.f);
            float v2 = fmaxf(ua.z - qa.z + acc[i][2] + bias[n + 2], 0.f);
            float v3 = fmaxf(ua.w - qa.w + acc[i][3] + bias[n + 3], 0.f);
            ushort4 o_;
            o_.x = f2bf(v0); o_.y = f2bf(v1); o_.z = f2bf(v2); o_.w = f2bf(v3);
            *(ushort4*)(outp + (size_t)m * NHID + n) = o_;
        }
        __syncthreads();
    }
}

// ---------------- per-batch mixing: out = relu(Ua + A@Ub + bias) ----------------
template <int OBF>
__global__ __launch_bounds__(256) void k_layer_agg(
    const float* __restrict__ Uab, const float* __restrict__ Abuf,
    const float* __restrict__ bias, void* __restrict__ outp, int Nc) {
    int b = blockIdx.x;
    int tid = threadIdx.x;
    __shared__ float Ast[64 * 68];
    __shared__ float Us[64 * 68];
    int ty = tid >> 4, tx = tid & 15;
    const float* Ab = Abuf + (size_t)b * 64 * 64;
    for (int e4 = tid; e4 < 1024; e4 += 256) {
        float4 v = *(const float4*)(Ab + e4 * 4);
        int row = e4 >> 4;
        int c4 = (e4 & 15) * 4;
        Ast[(c4 + 0) * 68 + row] = v.x;
        Ast[(c4 + 1) * 68 + row] = v.y;
        Ast[(c4 + 2) * 68 + row] = v.z;
        Ast[(c4 + 3) * 68 + row] = v.w;
    }
    int ldU = 2 * Nc;
    const float* Ua = Uab;
    const float* Ub = Uab + Nc;
    for (int n0 = 0; n0 < Nc; n0 += 64) {
        __syncthreads();
#pragma unroll
        for (int kq = 0; kq < 4; kq++) {
            int e4 = tid + kq * 256;
            int row = e4 >> 4;
            int c4 = (e4 & 15) * 4;
            float4 v = *(const float4*)(Ub + (size_t)(b * 64 + row) * ldU + n0 + c4);
            *(float4*)&Us[row * 68 + c4] = v;
        }
        __syncthreads();
        float acc[4][4];
#pragma unroll
        for (int i = 0; i < 4; i++)
#pragma unroll
            for (int j = 0; j < 4; j++) acc[i][j] = 0.f;
        for (int kk = 0; kk < 64; kk++) {
            float4 a4 = *(const float4*)&Ast[kk * 68 + ty * 4];
            float4 b4 = *(const float4*)&Us[kk * 68 + tx * 4];
            float aa[4] = {a4.x, a4.y, a4.z, a4.w};
            float bb[4] = {b4.x, b4.y, b4.z, b4.w};
#pragma unroll
            for (int i = 0; i < 4; i++)
#pragma unroll
                for (int j = 0; j < 4; j++) acc[i][j] += aa[i] * bb[j];
        }
#pragma unroll
        for (int i = 0; i < 4; i++) {
            int m = b * 64 + ty * 4 + i;
            int n = n0 + tx * 4;
            float4 ua = *(const float4*)(Ua + (size_t)m * ldU + n);
            float v0 = fmaxf(ua.x + acc[i][0] + bias[n + 0], 0.f);
            float v1 = fmaxf(ua.y + acc[i][1] + bias[n + 1], 0.f);
            float v2 = fmaxf(ua.z + acc[i][2] + bias[n + 2], 0.f);
            float v3 = fmaxf(ua.w + acc[i][3] + bias[n + 3], 0.f);
            if (OBF) {
                ushort4 o_;
                o_.x = f2bf(v0); o_.y = f2bf(v1); o_.z = f2bf(v2); o_.w = f2bf(v3);
                *(ushort4*)((unsigned short*)outp + (size_t)m * Nc + n) = o_;
            } else {
                float4 o_ = {v0, v1, v2, v3};
                *(float4*)((float*)outp + (size_t)m * Nc + n) = o_;
            }
        }
        __syncthreads();
    }
}

// ---------------- logits + 2-class softmax ----------------
__global__ __launch_bounds__(256) void k_logits(
    const float* __restrict__ h, const float* __restrict__ Wc2,
    const float* __restrict__ bc2, float* __restrict__ pred) {
    __shared__ float p0[256], p1[256];
    int tid = threadIdx.x;
    int r = tid >> 2, s = tid & 3;
    int m = blockIdx.x * 64 + r;
    const float* hr = h + (size_t)m * 256;
    float l0 = 0.f, l1 = 0.f;
    for (int k = s; k < 256; k += 4) {
        float hv = hr[k];
        l0 += hv * Wc2[2 * k];
        l1 += hv * Wc2[2 * k + 1];
    }
    p0[tid] = l0;
    p1[tid] = l1;
    __syncthreads();
    if (s == 0) {
        float L0 = p0[tid] + p0[tid + 1] + p0[tid + 2] + p0[tid + 3] + bc2[0];
        float L1 = p1[tid] + p1[tid + 1] + p1[tid + 2] + p1[tid + 3] + bc2[1];
        float mx = fmaxf(L0, L1);
        float e0 = expf(L0 - mx), e1 = expf(L1 - mx);
        float inv = 1.f / (e0 + e1);
        pred[2 * m] = e0 * inv;
        pred[2 * m + 1] = e1 * inv;
    }
}

// ---------------- launch ----------------
extern "C" void kernel_launch(void* const* d_in, const int* in_sizes, int n_in,
                              void* d_out, int out_size, void* d_ws, size_t ws_size,
                              hipStream_t stream) {
    const int* indexes = (const int*)d_in[0];
    const float* features = (const float*)d_in[1];
    const int* labels = (const int*)d_in[2];
    const int* knn = (const int*)d_in[5];
    const float* all_pred = (const float*)d_in[6];
    const float* W1 = (const float*)d_in[7];
    const float* b1 = (const float*)d_in[8];
    const float* W2 = (const float*)d_in[9];
    const float* b2 = (const float*)d_in[10];
    const float* Wc1 = (const float*)d_in[11];
    const float* bc1 = (const float*)d_in[12];
    const float* pre_a = (const float*)d_in[13];
    const float* Wc2 = (const float*)d_in[14];
    const float* bc2 = (const float*)d_in[15];
    float* out = (float*)d_out;

    char* w = (char*)d_ws;
    size_t o = 0;
    auto carve = [&](size_t bytes) -> char* {
        char* p = w + o;
        o += (bytes + 255) & ~(size_t)255;
        return p;
    };
    int* cnt = (int*)carve((size_t)Cc * 4);
    int* off = (int*)carve((size_t)Cc * 4);
    int* pos = (int*)carve((size_t)Cc * 4);
    int* rowidx = (int*)carve((size_t)Nn * 4);
    float* clu_mean = (float*)carve((size_t)Cc * Dd * 4);                       // 41 MB
    unsigned short* PA = (unsigned short*)carve((size_t)MP * Dd * 2);           // 22 MB
    float* Pout = (float*)carve((size_t)MP * 2 * NHID * 4);                     // 22 MB
    float* Abuf = (float*)carve((size_t)Bq * Kn * Kn * 4);                      // 4.2 MB
    unsigned short* Bp1 = (unsigned short*)carve((size_t)(Dd / 8) * 1024 * 8 * 2);   // 4.2 MB
    unsigned short* x1 = (unsigned short*)carve((size_t)Bq * Kn * NHID * 2);    // 16.8 MB
    float* V = (float*)carve((size_t)Bq * Kn * 2 * H2d * 4);                    // 33.6 MB
    unsigned short* Bp2 = (unsigned short*)carve((size_t)(NHID / 8) * 512 * 8 * 2);  // 0.52 MB
    unsigned short* x2 = (unsigned short*)carve((size_t)Bq * Kn * H2d * 2);     // 8.4 MB
    float* h = (float*)carve((size_t)Bq * Kn * H2d * 4);                        // 16.8 MB
    unsigned short* Bpc = (unsigned short*)carve((size_t)(H2d / 8) * 256 * 8 * 2);   // 0.13 MB

    float* simm_out = out + (size_t)Bq * Kn * 2;

    // 1) cluster bucketing
    k_zero_int<<<(Cc + 255) / 256, 256, 0, stream>>>(cnt, Cc);
    k_count<<<(Nn + 255) / 256, 256, 0, stream>>>(labels, cnt, Nn);
    k_scan<<<1, 1024, 0, stream>>>(cnt, off, pos, Cc);
    k_scatter<<<(Nn + 255) / 256, 256, 0, stream>>>(labels, pos, rowidx, Nn);

    // 1b) zero the PA pad rows [5000,5120) so the GEMM never sees poison
    {
        int npad = (PIVROW - Cc) * Dd / 2;   // shorts -> ints
        k_zero_int<<<(npad + 255) / 256, 256, 0, stream>>>(
            (int*)(PA + (size_t)Cc * Dd), npad);
    }

    // 2) cluster means + simm output + normalized means (bf16 rows of PA)
    k_meansimm<<<Cc, 256, 0, stream>>>(features, rowidx, off, cnt, clu_mean,
                                       simm_out, PA);

    // 2b) normalized pivots into PA rows [5120,5376)
    k_pivots<<<Bq, 256, 0, stream>>>(features, indexes, PA);

    // 3) per-batch adjacency (MFMA hi/lo gram)
    k_build_ax<<<Bq, 256, 0, stream>>>(features, clu_mean, labels, indexes, knn,
                                       all_pred, Abuf);

    // 3b) weight packs (bf16 MFMA-native)
    k_pack_w<1><<<(Dd / 8) * 1024 / 256, 256, 0, stream>>>(W1, Bp1, Dd, NHID);
    k_pack_w<1><<<(NHID / 8) * 512 / 256, 256, 0, stream>>>(W2, Bp2, NHID, H2d);
    k_pack_w<0><<<(H2d / 8) * 256 / 256, 256, 0, stream>>>(Wc1, Bpc, H2d, H2d);

    // 4) Pout = PA @ [W1a | W1b]  (M=5376, K=2048, N=1024)
    {
        dim3 g(1024 / 128, MP / 128);
        gemm_bf16_mfma<0><<<g, 256, 0, stream>>>(PA, Bp1, Pout, MP, Dd, 1024,
                                                 nullptr, nullptr);
    }
    // 5) x1 = relu((Pa-Qa) + A@(Pb-Qb) + b1) via gather -> bf16
    k_layer_agg1<<<Bq, 256, 0, stream>>>(Pout, Abuf, labels, knn, b1, x1);

    // 6) V = [x1 @ W2a | x1 @ W2b]  (M=16384, K=512, N=512)
    {
        dim3 g(512 / 128, (Bq * Kn) / 128);
        gemm_bf16_mfma<0><<<g, 256, 0, stream>>>(x1, Bp2, V, Bq * Kn, NHID, 512,
                                                 nullptr, nullptr);
    }
    // 7) x2 = relu(Va + A@Vb + b2)  -> bf16
    k_layer_agg<1><<<Bq, 256, 0, stream>>>(V, Abuf, b2, x2, H2d);

    // 8) h = prelu(x2 @ Wc1 + bc1)  (M=16384, K=256, N=256, fused epilogue)
    {
        dim3 g(256 / 128, (Bq * Kn) / 128);
        gemm_bf16_mfma<1><<<g, 256, 0, stream>>>(x2, Bpc, h, Bq * Kn, H2d, 256,
                                                 bc1, pre_a);
    }
    // 9) logits + softmax -> pred
    k_logits<<<(Bq * Kn) / 64, 256, 0, stream>>>(h, Wc2, bc2, out);

    (void)in_sizes; (void)n_in; (void)out_size; (void)ws_size;
}

// Round 2
// 829.742 us; speedup vs baseline: 1.0927x; 1.0092x over previous
//
#include <hip/hip_runtime.h>
#include <math.h>

#define Bq 256
#define Kn 64
#define Dd 2048
#define Nn 50000
#define Cc 5000
#define NHID 512
#define H2d 256
#define LDH 264   // padded LDS row stride (shorts) for gram staging
#define MP 5376   // padded P-matrix rows: 5000 cn + 120 pad + 256 pivots
#define PIVROW 5120

typedef __attribute__((ext_vector_type(8))) __bf16 bf16x8;
typedef __attribute__((ext_vector_type(4))) float f32x4;

__device__ __forceinline__ unsigned short f2bf(float f) {
    union { float f; unsigned int u; } v;
    v.f = f;
    unsigned int u = v.u;
    unsigned int r = (u + 0x7fff + ((u >> 16) & 1)) >> 16;   // RNE
    return (unsigned short)r;
}
__device__ __forceinline__ float bf2f(unsigned short h) {
    union { unsigned int u; float f; } v;
    v.u = ((unsigned int)h) << 16;
    return v.f;
}

// ---------------- merged zero kernel ----------------
__global__ void k_zero_multi(int* __restrict__ p0, int n0,
                             int* __restrict__ p1, int n1,
                             int* __restrict__ p2, int n2,
                             int* __restrict__ p3, int n3) {
    int i = blockIdx.x * 256 + threadIdx.x;
    if (i < n0) { p0[i] = 0; return; }
    i -= n0;
    if (i < n1) { p1[i] = 0; return; }
    i -= n1;
    if (i < n2) { p2[i] = 0; return; }
    i -= n2;
    if (i < n3) p3[i] = 0;
}

__global__ void k_count(const int* __restrict__ labels, int* __restrict__ cnt, int n) {
    int i = blockIdx.x * 256 + threadIdx.x;
    if (i < n) atomicAdd(&cnt[labels[i]], 1);
}

// atomic segment allocator: contiguous (unordered) cluster offsets
__global__ void k_alloc(const int* __restrict__ cnt, int* __restrict__ off,
                        int* __restrict__ pos, int* __restrict__ total, int C) {
    int c = blockIdx.x * 256 + threadIdx.x;
    if (c < C) {
        int o = atomicAdd(total, cnt[c]);
        off[c] = o;
        pos[c] = o;
    }
}

__global__ void k_scatter(const int* __restrict__ labels, int* __restrict__ pos,
                          int* __restrict__ rowidx, int n) {
    int i = blockIdx.x * 256 + threadIdx.x;
    if (i < n) {
        int p = atomicAdd(&pos[labels[i]], 1);
        rowidx[p] = i;
    }
}

// ---------------- cluster mean + simm + normalized-mean (bf16); pivot rows merged ----------------
__global__ __launch_bounds__(256) void k_meansimm(
    const float* __restrict__ feat, const int* __restrict__ rowidx,
    const int* __restrict__ off, const int* __restrict__ cnt,
    const int* __restrict__ indexes,
    float* __restrict__ clu_mean, float* __restrict__ simm,
    unsigned short* __restrict__ PA) {
    int c = blockIdx.x;
    int t = threadIdx.x;
    __shared__ float red[256];

    if (c >= Cc) {
        // pivot path: normalized raw feature row -> PA[PIVROW + b]
        int b = c - Cc;
        const float* row = feat + (size_t)indexes[b] * Dd;
        float4 v0 = *(const float4*)(row + t * 4);
        float4 v1 = *(const float4*)(row + 1024 + t * 4);
        float ss = v0.x * v0.x + v0.y * v0.y + v0.z * v0.z + v0.w * v0.w +
                   v1.x * v1.x + v1.y * v1.y + v1.z * v1.z + v1.w * v1.w;
        red[t] = ss;
        __syncthreads();
        for (int s2 = 128; s2 > 0; s2 >>= 1) {
            if (t < s2) red[t] += red[t + s2];
            __syncthreads();
        }
        float tot = red[0];
        float rnn = (tot > 0.f) ? rsqrtf(tot) : 0.f;
        ushort4 c0, c1;
        c0.x = f2bf(v0.x * rnn); c0.y = f2bf(v0.y * rnn);
        c0.z = f2bf(v0.z * rnn); c0.w = f2bf(v0.w * rnn);
        c1.x = f2bf(v1.x * rnn); c1.y = f2bf(v1.y * rnn);
        c1.z = f2bf(v1.z * rnn); c1.w = f2bf(v1.w * rnn);
        unsigned short* cr = PA + (size_t)(PIVROW + b) * Dd;
        *(ushort4*)(cr + t * 4) = c0;
        *(ushort4*)(cr + 1024 + t * 4) = c1;
        return;
    }

    int n = cnt[c], st = off[c];
    float4 a0 = {0.f, 0.f, 0.f, 0.f}, a1 = {0.f, 0.f, 0.f, 0.f};
    for (int r = 0; r < n; r++) {
        const float* row = feat + (size_t)rowidx[st + r] * Dd;
        float4 v0 = *(const float4*)(row + t * 4);
        float4 v1 = *(const float4*)(row + 1024 + t * 4);
        a0.x += v0.x; a0.y += v0.y; a0.z += v0.z; a0.w += v0.w;
        a1.x += v1.x; a1.y += v1.y; a1.z += v1.z; a1.w += v1.w;
    }
    float sc = 1.f / (float)(n > 1 ? n : 1);
    a0.x *= sc; a0.y *= sc; a0.z *= sc; a0.w *= sc;
    a1.x *= sc; a1.y *= sc; a1.z *= sc; a1.w *= sc;
    float* outr = clu_mean + (size_t)c * Dd;
    *(float4*)(outr + t * 4) = a0;
    *(float4*)(outr + 1024 + t * 4) = a1;
    float ss = a0.x * a0.x + a0.y * a0.y + a0.z * a0.z + a0.w * a0.w +
               a1.x * a1.x + a1.y * a1.y + a1.z * a1.z + a1.w * a1.w;
    red[t] = ss;
    __syncthreads();
    for (int s2 = 128; s2 > 0; s2 >>= 1) {
        if (t < s2) red[t] += red[t + s2];
        __syncthreads();
    }
    if (t == 0) simm[c] = red[0];
    float tot = red[0];
    float rnn = (tot > 0.f) ? rsqrtf(tot) : 0.f;
    ushort4 c0, c1;
    c0.x = f2bf(a0.x * rnn); c0.y = f2bf(a0.y * rnn);
    c0.z = f2bf(a0.z * rnn); c0.w = f2bf(a0.w * rnn);
    c1.x = f2bf(a1.x * rnn); c1.y = f2bf(a1.y * rnn);
    c1.z = f2bf(a1.z * rnn); c1.w = f2bf(a1.w * rnn);
    unsigned short* cr = PA + (size_t)c * Dd;
    *(ushort4*)(cr + t * 4) = c0;
    *(ushort4*)(cr + 1024 + t * 4) = c1;
}

// ---------------- per-batch: A (MFMA hi/lo gram) ----------------
__global__ __launch_bounds__(256) void k_build_ax(
    const float* __restrict__ feat, const float* __restrict__ clu_mean,
    const int* __restrict__ labels, const int* __restrict__ indexes,
    const int* __restrict__ knn, const float* __restrict__ all_pred,
    float* __restrict__ Abuf) {
    __shared__ unsigned short Hs[64 * LDH];
    __shared__ unsigned short Ls[64 * LDH];
    __shared__ float Gs[64 * 65];
    __shared__ const float* rowp[64];
    __shared__ float wj64[64];

    int b = blockIdx.x, tid = threadIdx.x;
    int wave = tid >> 6, lane = tid & 63, quad = lane >> 4, l16 = lane & 15;

    if (tid < 64) {
        const float* p = (tid == 0) ? feat + (size_t)indexes[b] * Dd
                                    : clu_mean + (size_t)labels[knn[b * 64 + tid]] * Dd;
        rowp[tid] = p;
        wj64[tid] = expf(all_pred[(b * 64 + tid) * 2 + 1]);
    }
    __syncthreads();

    f32x4 acc[4];
#pragma unroll
    for (int j = 0; j < 4; j++) acc[j] = (f32x4){0.f, 0.f, 0.f, 0.f};

    for (int ch = 0; ch < 8; ch++) {
        int d0 = ch * 256;
        __syncthreads();
#pragma unroll
        for (int q = 0; q < 16; q++) {
            int e4 = tid + q * 256;
            int row = e4 >> 6;
            int c4 = (e4 & 63) * 4;
            float4 v = *(const float4*)(rowp[row] + d0 + c4);
            ushort4 h, l;
            h.x = f2bf(v.x); l.x = f2bf(v.x - bf2f(h.x));
            h.y = f2bf(v.y); l.y = f2bf(v.y - bf2f(h.y));
            h.z = f2bf(v.z); l.z = f2bf(v.z - bf2f(h.z));
            h.w = f2bf(v.w); l.w = f2bf(v.w - bf2f(h.w));
            *(ushort4*)&Hs[row * LDH + c4] = h;
            *(ushort4*)&Ls[row * LDH + c4] = l;
        }
        __syncthreads();
#pragma unroll
        for (int ks = 0; ks < 8; ks++) {
            int kk = ks * 32 + quad * 8;
            bf16x8 ah = *(const bf16x8*)&Hs[(wave * 16 + l16) * LDH + kk];
            bf16x8 al = *(const bf16x8*)&Ls[(wave * 16 + l16) * LDH + kk];
#pragma unroll
            for (int j = 0; j < 4; j++) {
                bf16x8 bh = *(const bf16x8*)&Hs[(j * 16 + l16) * LDH + kk];
                bf16x8 bl = *(const bf16x8*)&Ls[(j * 16 + l16) * LDH + kk];
                acc[j] = __builtin_amdgcn_mfma_f32_16x16x32_bf16(ah, bh, acc[j], 0, 0, 0);
                acc[j] = __builtin_amdgcn_mfma_f32_16x16x32_bf16(ah, bl, acc[j], 0, 0, 0);
                acc[j] = __builtin_amdgcn_mfma_f32_16x16x32_bf16(al, bh, acc[j], 0, 0, 0);
            }
        }
    }
    __syncthreads();
#pragma unroll
    for (int j = 0; j < 4; j++)
#pragma unroll
        for (int r = 0; r < 4; r++)
            Gs[(wave * 16 + quad * 4 + r) * 65 + j * 16 + l16] = acc[j][r];
    __syncthreads();
    if (tid < 64) {
        int r = tid;
        float mx = -1e30f;
        for (int c = 0; c < 64; c++) {
            float v = Gs[r * 65 + c] * wj64[c];
            mx = fmaxf(mx, v);
        }
        float s = 0.f;
        for (int c = 0; c < 64; c++) {
            float e = expf(Gs[r * 65 + c] * wj64[c] - mx);
            Gs[r * 65 + c] = e;
            s += e;
        }
        float inv = 1.f / s;
        float* Arow = Abuf + ((size_t)b * 64 + r) * 64;
        for (int c = 0; c < 64; c++) Arow[c] = Gs[r * 65 + c] * inv;
    }
}

// ---------------- merged weight repack ----------------
__device__ __forceinline__ void pack_item(const float* __restrict__ W,
                                          unsigned short* __restrict__ Bp,
                                          int K, int Nhalf, int split, int idx) {
    int Ntot = split ? 2 * Nhalf : Nhalf;
    int kb = idx / Ntot;
    int n = idx - kb * Ntot;
    float v[8];
#pragma unroll
    for (int j = 0; j < 8; j++) {
        int k = kb * 8 + j;
        if (split)
            v[j] = (n < Nhalf) ? W[(size_t)k * Nhalf + n]
                               : W[(size_t)(K + k) * Nhalf + (n - Nhalf)];
        else
            v[j] = W[(size_t)k * Nhalf + n];
    }
    ushort4 lo, hi;
    lo.x = f2bf(v[0]); lo.y = f2bf(v[1]); lo.z = f2bf(v[2]); lo.w = f2bf(v[3]);
    hi.x = f2bf(v[4]); hi.y = f2bf(v[5]); hi.z = f2bf(v[6]); hi.w = f2bf(v[7]);
    *(ushort4*)&Bp[(size_t)idx * 8] = lo;
    *(ushort4*)&Bp[(size_t)idx * 8 + 4] = hi;
}

// blocks [0,1024): W1 split-pack; [1024,1152): W2 straight (K=1024); [1152,1184): Wc1
__global__ __launch_bounds__(256) void k_pack_all(
    const float* __restrict__ W1, const float* __restrict__ W2,
    const float* __restrict__ Wc1, unsigned short* __restrict__ Bp1,
    unsigned short* __restrict__ Bp2, unsigned short* __restrict__ Bpc) {
    int blk = blockIdx.x;
    int tid = threadIdx.x;
    if (blk < 1024) {
        pack_item(W1, Bp1, Dd, NHID, 1, blk * 256 + tid);
    } else if (blk < 1024 + 128) {
        pack_item(W2, Bp2, 2 * NHID, H2d, 0, (blk - 1024) * 256 + tid);
    } else {
        pack_item(Wc1, Bpc, H2d, H2d, 0, (blk - 1152) * 256 + tid);
    }
}

// ---------------- bf16 MFMA GEMM (m97 structure), 3 epilogues ----------------
// EPI 0: f32 store.  EPI 2: relu(v+bias) -> bf16 store.
// EPI 3: prelu(v+bias), dot with Wc2 -> atomicAdd logits (no C store).
template <int EPI>
__global__ __launch_bounds__(256) void gemm_bf16_mfma(
    const unsigned short* __restrict__ A, const unsigned short* __restrict__ Bp,
    void* __restrict__ Cout, int M, int K, int N,
    const float* __restrict__ bias, const float* __restrict__ pre_a,
    const float* __restrict__ wc2, float* __restrict__ lbuf) {
    __shared__ unsigned short Asm[128 * 32];
    __shared__ unsigned short Bsm[4 * 128 * 8];
    int tid = threadIdx.x;
    int wave = tid >> 6, lane = tid & 63;
    int quad = lane >> 4, l16 = lane & 15;
    int m0 = blockIdx.y * 128, n0 = blockIdx.x * 128;
    int wm = (wave >> 1) * 64, wn = (wave & 1) * 64;

    f32x4 acc[4][4];
#pragma unroll
    for (int i = 0; i < 4; i++)
#pragma unroll
        for (int j = 0; j < 4; j++) acc[i][j] = (f32x4){0.f, 0.f, 0.f, 0.f};

    int ia0 = wave * 2, ia1 = wave * 2 + 1;
    const unsigned short* gA0 = A + (size_t)(m0 + ia0 * 16 + (lane >> 2)) * K + (lane & 3) * 8;
    const unsigned short* gA1 = gA0 + (size_t)16 * K;
    const unsigned short* gB0 = Bp + (size_t)(n0 + lane) * 8 + (size_t)wave * N * 8;

    for (int k0 = 0; k0 < K; k0 += 32) {
        __syncthreads();
        size_t bko = (size_t)(k0 >> 3) * N * 8;
        __builtin_amdgcn_global_load_lds(
            (const __attribute__((address_space(1))) void*)(gA0 + k0),
            (__attribute__((address_space(3))) void*)(Asm + ia0 * 512), 16, 0, 0);
        __builtin_amdgcn_global_load_lds(
            (const __attribute__((address_space(1))) void*)(gA1 + k0),
            (__attribute__((address_space(3))) void*)(Asm + ia1 * 512), 16, 0, 0);
        __builtin_amdgcn_global_load_lds(
            (const __attribute__((address_space(1))) void*)(gB0 + bko),
            (__attribute__((address_space(3))) void*)(Bsm + wave * 1024), 16, 0, 0);
        __builtin_amdgcn_global_load_lds(
            (const __attribute__((address_space(1))) void*)(gB0 + bko + 512),
            (__attribute__((address_space(3))) void*)(Bsm + wave * 1024 + 512), 16, 0, 0);
        __syncthreads();

        bf16x8 a[4], b[4];
#pragma unroll
        for (int i = 0; i < 4; i++)
            a[i] = *(const bf16x8*)&Asm[(wm + i * 16 + l16) * 32 + quad * 8];
#pragma unroll
        for (int j = 0; j < 4; j++)
            b[j] = *(const bf16x8*)&Bsm[quad * 1024 + (wn + j * 16 + l16) * 8];
#pragma unroll
        for (int i = 0; i < 4; i++)
#pragma unroll
            for (int j = 0; j < 4; j++)
                acc[i][j] = __builtin_amdgcn_mfma_f32_16x16x32_bf16(
                    a[i], b[j], acc[i][j], 0, 0, 0);
    }

    if (EPI == 0) {
        float* C = (float*)Cout;
#pragma unroll
        for (int i = 0; i < 4; i++)
#pragma unroll
            for (int j = 0; j < 4; j++) {
                int col = n0 + wn + j * 16 + l16;
#pragma unroll
                for (int r = 0; r < 4; r++) {
                    int row = m0 + wm + i * 16 + quad * 4 + r;
                    C[(size_t)row * N + col] = acc[i][j][r];
                }
            }
    } else if (EPI == 2) {
        unsigned short* C = (unsigned short*)Cout;
#pragma unroll
        for (int i = 0; i < 4; i++)
#pragma unroll
            for (int j = 0; j < 4; j++) {
                int col = n0 + wn + j * 16 + l16;
                float bcol = bias[col];
#pragma unroll
                for (int r = 0; r < 4; r++) {
                    int row = m0 + wm + i * 16 + quad * 4 + r;
                    float v = acc[i][j][r] + bcol;
                    v = fmaxf(v, 0.f);
                    C[(size_t)row * N + col] = f2bf(v);
                }
            }
    } else {  // EPI == 3: prelu + logit dot, reduce across l16, atomicAdd
#pragma unroll
        for (int i = 0; i < 4; i++) {
#pragma unroll
            for (int r = 0; r < 4; r++) {
                float l0 = 0.f, l1 = 0.f;
#pragma unroll
                for (int j = 0; j < 4; j++) {
                    int col = n0 + wn + j * 16 + l16;
                    float v = acc[i][j][r] + bias[col];
                    v = (v >= 0.f) ? v : pre_a[col] * v;
                    l0 += v * wc2[2 * col];
                    l1 += v * wc2[2 * col + 1];
                }
#pragma unroll
                for (int mm = 1; mm < 16; mm <<= 1) {
                    l0 += __shfl_xor(l0, mm, 64);
                    l1 += __shfl_xor(l1, mm, 64);
                }
                if (l16 == 0) {
                    int row = m0 + wm + i * 16 + quad * 4 + r;
                    atomicAdd(&lbuf[2 * row], l0);
                    atomicAdd(&lbuf[2 * row + 1], l1);
                }
            }
        }
    }
}

// ---------------- layer-1 mixing with P/Q gather -> xy1 lower half ----------------
__global__ __launch_bounds__(256) void k_layer_agg1(
    const float* __restrict__ P, const float* __restrict__ Abuf,
    const int* __restrict__ labels, const int* __restrict__ knn,
    const float* __restrict__ bias, unsigned short* __restrict__ outp) {
    int b = blockIdx.x;
    int half = blockIdx.y;
    int tid = threadIdx.x;
    __shared__ float Ast[64 * 68];
    __shared__ float Us[64 * 68];
    __shared__ int rowid[64];
    int ty = tid >> 4, tx = tid & 15;
    if (tid < 64)
        rowid[tid] = (tid == 0) ? (PIVROW + b) : labels[knn[b * 64 + tid]];
    const float* Ab = Abuf + (size_t)b * 64 * 64;
    for (int e4 = tid; e4 < 1024; e4 += 256) {
        float4 v = *(const float4*)(Ab + e4 * 4);
        int row = e4 >> 4;
        int c4 = (e4 & 15) * 4;
        Ast[(c4 + 0) * 68 + row] = v.x;
        Ast[(c4 + 1) * 68 + row] = v.y;
        Ast[(c4 + 2) * 68 + row] = v.z;
        Ast[(c4 + 3) * 68 + row] = v.w;
    }
    const float* Q = P + (size_t)(PIVROW + b) * 1024;
    for (int n0 = half * (NHID / 2); n0 < (half + 1) * (NHID / 2); n0 += 64) {
        __syncthreads();
#pragma unroll
        for (int kq = 0; kq < 4; kq++) {
            int e4 = tid + kq * 256;
            int row = e4 >> 4;
            int c4 = (e4 & 15) * 4;
            float4 v = *(const float4*)(P + (size_t)rowid[row] * 1024 + NHID + n0 + c4);
            float4 q = *(const float4*)(Q + NHID + n0 + c4);
            v.x -= q.x; v.y -= q.y; v.z -= q.z; v.w -= q.w;
            *(float4*)&Us[row * 68 + c4] = v;
        }
        __syncthreads();
        float acc[4][4];
#pragma unroll
        for (int i = 0; i < 4; i++)
#pragma unroll
            for (int j = 0; j < 4; j++) acc[i][j] = 0.f;
        for (int kk = 0; kk < 64; kk++) {
            float4 a4 = *(const float4*)&Ast[kk * 68 + ty * 4];
            float4 b4 = *(const float4*)&Us[kk * 68 + tx * 4];
            float aa[4] = {a4.x, a4.y, a4.z, a4.w};
            float bb[4] = {b4.x, b4.y, b4.z, b4.w};
#pragma unroll
            for (int i = 0; i < 4; i++)
#pragma unroll
                for (int j = 0; j < 4; j++) acc[i][j] += aa[i] * bb[j];
        }
#pragma unroll
        for (int i = 0; i < 4; i++) {
            int krow = ty * 4 + i;
            int m = b * 64 + krow;
            int n = n0 + tx * 4;
            float4 ua = *(const float4*)(P + (size_t)rowid[krow] * 1024 + n);
            float4 qa = *(const float4*)(Q + n);
            float v0 = fmaxf(ua.x - qa.x + acc[i][0] + bias[n + 0], 0.f);
            float v1 = fmaxf(ua.y - qa.y + acc[i][1] + bias[n + 1], 0.f);
            float v2 = fmaxf(ua.z - qa.z + acc[i][2] + bias[n + 2], 0.f);
            float v3 = fmaxf(ua.w - qa.w + acc[i][3] + bias[n + 3], 0.f);
            ushort4 o_;
            o_.x = f2bf(v0); o_.y = f2bf(v1); o_.z = f2bf(v2); o_.w = f2bf(v3);
            *(ushort4*)(outp + (size_t)m * 1024 + n) = o_;
        }
        __syncthreads();
    }
}

// ---------------- premix: y1 = A @ x1 -> xy1 upper half (bf16) ----------------
__global__ __launch_bounds__(256) void k_premix(
    const unsigned short* __restrict__ xy1, const float* __restrict__ Abuf,
    unsigned short* __restrict__ yout) {
    int b = blockIdx.x;
    int half = blockIdx.y;
    int tid = threadIdx.x;
    __shared__ float Ast[64 * 68];
    __shared__ float Us[64 * 68];
    int ty = tid >> 4, tx = tid & 15;
    const float* Ab = Abuf + (size_t)b * 64 * 64;
    for (int e4 = tid; e4 < 1024; e4 += 256) {
        float4 v = *(const float4*)(Ab + e4 * 4);
        int row = e4 >> 4;
        int c4 = (e4 & 15) * 4;
        Ast[(c4 + 0) * 68 + row] = v.x;
        Ast[(c4 + 1) * 68 + row] = v.y;
        Ast[(c4 + 2) * 68 + row] = v.z;
        Ast[(c4 + 3) * 68 + row] = v.w;
    }
    for (int n0 = half * (NHID / 2); n0 < (half + 1) * (NHID / 2); n0 += 64) {
        __syncthreads();
#pragma unroll
        for (int kq = 0; kq < 4; kq++) {
            int e4 = tid + kq * 256;
            int row = e4 >> 4;
            int c4 = (e4 & 15) * 4;
            ushort4 u = *(const ushort4*)(xy1 + (size_t)(b * 64 + row) * 1024 + n0 + c4);
            Us[row * 68 + c4 + 0] = bf2f(u.x);
            Us[row * 68 + c4 + 1] = bf2f(u.y);
            Us[row * 68 + c4 + 2] = bf2f(u.z);
            Us[row * 68 + c4 + 3] = bf2f(u.w);
        }
        __syncthreads();
        float acc[4][4];
#pragma unroll
        for (int i = 0; i < 4; i++)
#pragma unroll
            for (int j = 0; j < 4; j++) acc[i][j] = 0.f;
        for (int kk = 0; kk < 64; kk++) {
            float4 a4 = *(const float4*)&Ast[kk * 68 + ty * 4];
            float4 b4 = *(const float4*)&Us[kk * 68 + tx * 4];
            float aa[4] = {a4.x, a4.y, a4.z, a4.w};
            float bb[4] = {b4.x, b4.y, b4.z, b4.w};
#pragma unroll
            for (int i = 0; i < 4; i++)
#pragma unroll
                for (int j = 0; j < 4; j++) acc[i][j] += aa[i] * bb[j];
        }
#pragma unroll
        for (int i = 0; i < 4; i++) {
            int m = b * 64 + ty * 4 + i;
            int n = n0 + tx * 4;
            ushort4 o_;
            o_.x = f2bf(acc[i][0]);
            o_.y = f2bf(acc[i][1]);
            o_.z = f2bf(acc[i][2]);
            o_.w = f2bf(acc[i][3]);
            *(ushort4*)(yout + (size_t)m * 1024 + 512 + n) = o_;
        }
        __syncthreads();
    }
}

// ---------------- 2-class softmax from accumulated logits ----------------
__global__ void k_soft2(const float* __restrict__ lbuf, const float* __restrict__ bc2,
                        float* __restrict__ pred) {
    int m = blockIdx.x * 256 + threadIdx.x;
    if (m < Bq * Kn) {
        float L0 = lbuf[2 * m] + bc2[0];
        float L1 = lbuf[2 * m + 1] + bc2[1];
        float mx = fmaxf(L0, L1);
        float e0 = expf(L0 - mx), e1 = expf(L1 - mx);
        float inv = 1.f / (e0 + e1);
        pred[2 * m] = e0 * inv;
        pred[2 * m + 1] = e1 * inv;
    }
}

// ---------------- launch ----------------
extern "C" void kernel_launch(void* const* d_in, const int* in_sizes, int n_in,
                              void* d_out, int out_size, void* d_ws, size_t ws_size,
                              hipStream_t stream) {
    const int* indexes = (const int*)d_in[0];
    const float* features = (const float*)d_in[1];
    const int* labels = (const int*)d_in[2];
    const int* knn = (const int*)d_in[5];
    const float* all_pred = (const float*)d_in[6];
    const float* W1 = (const float*)d_in[7];
    const float* b1 = (const float*)d_in[8];
    const float* W2 = (const float*)d_in[9];
    const float* b2 = (const float*)d_in[10];
    const float* Wc1 = (const float*)d_in[11];
    const float* bc1 = (const float*)d_in[12];
    const float* pre_a = (const float*)d_in[13];
    const float* Wc2 = (const float*)d_in[14];
    const float* bc2 = (const float*)d_in[15];
    float* out = (float*)d_out;

    char* w = (char*)d_ws;
    size_t o = 0;
    auto carve = [&](size_t bytes) -> char* {
        char* p = w + o;
        o += (bytes + 255) & ~(size_t)255;
        return p;
    };
    int* cnt = (int*)carve((size_t)Cc * 4);
    int* off = (int*)carve((size_t)Cc * 4);
    int* pos = (int*)carve((size_t)Cc * 4);
    int* total = (int*)carve(4);
    int* rowidx = (int*)carve((size_t)Nn * 4);
    float* clu_mean = (float*)carve((size_t)Cc * Dd * 4);                       // 41 MB
    unsigned short* PA = (unsigned short*)carve((size_t)MP * Dd * 2);           // 22 MB
    float* Pout = (float*)carve((size_t)MP * 2 * NHID * 4);                     // 22 MB
    float* Abuf = (float*)carve((size_t)Bq * Kn * Kn * 4);                      // 4.2 MB
    unsigned short* Bp1 = (unsigned short*)carve((size_t)(Dd / 8) * 1024 * 8 * 2);   // 4.2 MB
    unsigned short* xy1 = (unsigned short*)carve((size_t)Bq * Kn * 1024 * 2);   // 33.6 MB
    unsigned short* Bp2 = (unsigned short*)carve((size_t)(2 * NHID / 8) * H2d * 8 * 2);  // 0.52 MB
    unsigned short* x2 = (unsigned short*)carve((size_t)Bq * Kn * H2d * 2);     // 8.4 MB
    unsigned short* Bpc = (unsigned short*)carve((size_t)(H2d / 8) * 256 * 8 * 2);   // 0.13 MB
    float* lbuf = (float*)carve((size_t)Bq * Kn * 2 * 4);                       // 0.13 MB

    float* simm_out = out + (size_t)Bq * Kn * 2;

    // 1) zero: cnt, PA pad rows, lbuf, alloc counter  (one kernel)
    {
        int nPad = (PIVROW - Cc) * Dd / 2;   // pad shorts -> ints
        int nLb = Bq * Kn * 2;               // floats -> ints (0 bits == 0.0f)
        int ntot = Cc + nPad + nLb + 1;
        k_zero_multi<<<(ntot + 255) / 256, 256, 0, stream>>>(
            cnt, Cc, (int*)(PA + (size_t)Cc * Dd), nPad, (int*)lbuf, nLb, total, 1);
    }
    k_count<<<(Nn + 255) / 256, 256, 0, stream>>>(labels, cnt, Nn);
    k_alloc<<<(Cc + 255) / 256, 256, 0, stream>>>(cnt, off, pos, total, Cc);
    k_scatter<<<(Nn + 255) / 256, 256, 0, stream>>>(labels, pos, rowidx, Nn);

    // 2) cluster means + simm + normalized means; pivot rows appended to grid
    k_meansimm<<<Cc + Bq, 256, 0, stream>>>(features, rowidx, off, cnt, indexes,
                                            clu_mean, simm_out, PA);

    // 3) per-batch adjacency (MFMA hi/lo gram)
    k_build_ax<<<Bq, 256, 0, stream>>>(features, clu_mean, labels, indexes, knn,
                                       all_pred, Abuf);

    // 3b) all weight packs in one launch
    k_pack_all<<<1184, 256, 0, stream>>>(W1, W2, Wc1, Bp1, Bp2, Bpc);

    // 4) Pout = PA @ [W1a | W1b]  (M=5376, K=2048, N=1024)
    {
        dim3 g(1024 / 128, MP / 128);
        gemm_bf16_mfma<0><<<g, 256, 0, stream>>>(PA, Bp1, Pout, MP, Dd, 1024,
                                                 nullptr, nullptr, nullptr, nullptr);
    }
    // 5) x1 = relu((Pa-Qa) + A@(Pb-Qb) + b1) -> xy1[:, 0:512] (bf16)
    {
        dim3 g(Bq, 2);
        k_layer_agg1<<<g, 256, 0, stream>>>(Pout, Abuf, labels, knn, b1, xy1);
    }
    // 5b) y1 = A @ x1 -> xy1[:, 512:1024] (bf16)
    {
        dim3 g(Bq, 2);
        k_premix<<<g, 256, 0, stream>>>(xy1, Abuf, xy1);
    }
    // 6) x2 = relu([x1|y1] @ W2 + b2)  (M=16384, K=1024, N=256) -> bf16
    {
        dim3 g(H2d / 128, (Bq * Kn) / 128);
        gemm_bf16_mfma<2><<<g, 256, 0, stream>>>(xy1, Bp2, x2, Bq * Kn, 1024, H2d,
                                                 b2, nullptr, nullptr, nullptr);
    }
    // 7) logits = prelu(x2 @ Wc1 + bc1) @ Wc2, accumulated into lbuf (no h buffer)
    {
        dim3 g(H2d / 128, (Bq * Kn) / 128);
        gemm_bf16_mfma<3><<<g, 256, 0, stream>>>(x2, Bpc, nullptr, Bq * Kn, H2d, H2d,
                                                 bc1, pre_a, Wc2, lbuf);
    }
    // 8) softmax -> pred
    k_soft2<<<(Bq * Kn + 255) / 256, 256, 0, stream>>>(lbuf, bc2, out);

    (void)in_sizes; (void)n_in; (void)out_size; (void)ws_size;
}

// Round 3
// 798.044 us; speedup vs baseline: 1.1361x; 1.0397x over previous
//
#include <hip/hip_runtime.h>
#include <math.h>

#define Bq 256
#define Kn 64
#define Dd 2048
#define Nn 50000
#define Cc 5000
#define NHID 512
#define H2d 256
#define LDH 264   // padded LDS row stride (shorts) for gram staging
#define MP 5376   // padded P-matrix rows: 5000 cn + 120 pad + 256 pivots
#define PIVROW 5120
#define LDA1 72   // LDS row stride (shorts) for gcn1 tiles (multiple of 8 for b128 align)

typedef __attribute__((ext_vector_type(8))) __bf16 bf16x8;
typedef __attribute__((ext_vector_type(4))) float f32x4;

__device__ __forceinline__ unsigned short f2bf(float f) {
    union { float f; unsigned int u; } v;
    v.f = f;
    unsigned int u = v.u;
    unsigned int r = (u + 0x7fff + ((u >> 16) & 1)) >> 16;   // RNE
    return (unsigned short)r;
}
__device__ __forceinline__ float bf2f(unsigned short h) {
    union { unsigned int u; float f; } v;
    v.u = ((unsigned int)h) << 16;
    return v.f;
}

// ---------------- merged zero kernel ----------------
__global__ void k_zero_multi(int* __restrict__ p0, int n0,
                             int* __restrict__ p1, int n1,
                             int* __restrict__ p2, int n2,
                             int* __restrict__ p3, int n3) {
    int i = blockIdx.x * 256 + threadIdx.x;
    if (i < n0) { p0[i] = 0; return; }
    i -= n0;
    if (i < n1) { p1[i] = 0; return; }
    i -= n1;
    if (i < n2) { p2[i] = 0; return; }
    i -= n2;
    if (i < n3) p3[i] = 0;
}

__global__ void k_count(const int* __restrict__ labels, int* __restrict__ cnt, int n) {
    int i = blockIdx.x * 256 + threadIdx.x;
    if (i < n) atomicAdd(&cnt[labels[i]], 1);
}

// atomic segment allocator: contiguous (unordered) cluster offsets
__global__ void k_alloc(const int* __restrict__ cnt, int* __restrict__ off,
                        int* __restrict__ pos, int* __restrict__ total, int C) {
    int c = blockIdx.x * 256 + threadIdx.x;
    if (c < C) {
        int o = atomicAdd(total, cnt[c]);
        off[c] = o;
        pos[c] = o;
    }
}

__global__ void k_scatter(const int* __restrict__ labels, int* __restrict__ pos,
                          int* __restrict__ rowidx, int n) {
    int i = blockIdx.x * 256 + threadIdx.x;
    if (i < n) {
        int p = atomicAdd(&pos[labels[i]], 1);
        rowidx[p] = i;
    }
}

// ---------------- cluster mean + simm + normalized-mean (bf16); pivot rows merged ----------------
__global__ __launch_bounds__(256) void k_meansimm(
    const float* __restrict__ feat, const int* __restrict__ rowidx,
    const int* __restrict__ off, const int* __restrict__ cnt,
    const int* __restrict__ indexes,
    float* __restrict__ clu_mean, float* __restrict__ simm,
    unsigned short* __restrict__ PA) {
    int c = blockIdx.x;
    int t = threadIdx.x;
    __shared__ float red[256];

    if (c >= Cc) {
        // pivot path: normalized raw feature row -> PA[PIVROW + b]
        int b = c - Cc;
        const float* row = feat + (size_t)indexes[b] * Dd;
        float4 v0 = *(const float4*)(row + t * 4);
        float4 v1 = *(const float4*)(row + 1024 + t * 4);
        float ss = v0.x * v0.x + v0.y * v0.y + v0.z * v0.z + v0.w * v0.w +
                   v1.x * v1.x + v1.y * v1.y + v1.z * v1.z + v1.w * v1.w;
        red[t] = ss;
        __syncthreads();
        for (int s2 = 128; s2 > 0; s2 >>= 1) {
            if (t < s2) red[t] += red[t + s2];
            __syncthreads();
        }
        float tot = red[0];
        float rnn = (tot > 0.f) ? rsqrtf(tot) : 0.f;
        ushort4 c0, c1;
        c0.x = f2bf(v0.x * rnn); c0.y = f2bf(v0.y * rnn);
        c0.z = f2bf(v0.z * rnn); c0.w = f2bf(v0.w * rnn);
        c1.x = f2bf(v1.x * rnn); c1.y = f2bf(v1.y * rnn);
        c1.z = f2bf(v1.z * rnn); c1.w = f2bf(v1.w * rnn);
        unsigned short* cr = PA + (size_t)(PIVROW + b) * Dd;
        *(ushort4*)(cr + t * 4) = c0;
        *(ushort4*)(cr + 1024 + t * 4) = c1;
        return;
    }

    int n = cnt[c], st = off[c];
    float4 a0 = {0.f, 0.f, 0.f, 0.f}, a1 = {0.f, 0.f, 0.f, 0.f};
    for (int r = 0; r < n; r++) {
        const float* row = feat + (size_t)rowidx[st + r] * Dd;
        float4 v0 = *(const float4*)(row + t * 4);
        float4 v1 = *(const float4*)(row + 1024 + t * 4);
        a0.x += v0.x; a0.y += v0.y; a0.z += v0.z; a0.w += v0.w;
        a1.x += v1.x; a1.y += v1.y; a1.z += v1.z; a1.w += v1.w;
    }
    float sc = 1.f / (float)(n > 1 ? n : 1);
    a0.x *= sc; a0.y *= sc; a0.z *= sc; a0.w *= sc;
    a1.x *= sc; a1.y *= sc; a1.z *= sc; a1.w *= sc;
    float* outr = clu_mean + (size_t)c * Dd;
    *(float4*)(outr + t * 4) = a0;
    *(float4*)(outr + 1024 + t * 4) = a1;
    float ss = a0.x * a0.x + a0.y * a0.y + a0.z * a0.z + a0.w * a0.w +
               a1.x * a1.x + a1.y * a1.y + a1.z * a1.z + a1.w * a1.w;
    red[t] = ss;
    __syncthreads();
    for (int s2 = 128; s2 > 0; s2 >>= 1) {
        if (t < s2) red[t] += red[t + s2];
        __syncthreads();
    }
    if (t == 0) simm[c] = red[0];
    float tot = red[0];
    float rnn = (tot > 0.f) ? rsqrtf(tot) : 0.f;
    ushort4 c0, c1;
    c0.x = f2bf(a0.x * rnn); c0.y = f2bf(a0.y * rnn);
    c0.z = f2bf(a0.z * rnn); c0.w = f2bf(a0.w * rnn);
    c1.x = f2bf(a1.x * rnn); c1.y = f2bf(a1.y * rnn);
    c1.z = f2bf(a1.z * rnn); c1.w = f2bf(a1.w * rnn);
    unsigned short* cr = PA + (size_t)c * Dd;
    *(ushort4*)(cr + t * 4) = c0;
    *(ushort4*)(cr + 1024 + t * 4) = c1;
}

// ---------------- per-batch: A (MFMA hi/lo gram), 512 threads ----------------
__global__ __launch_bounds__(512) void k_build_ax(
    const float* __restrict__ feat, const float* __restrict__ clu_mean,
    const int* __restrict__ labels, const int* __restrict__ indexes,
    const int* __restrict__ knn, const float* __restrict__ all_pred,
    float* __restrict__ Abuf) {
    __shared__ unsigned short Hs[64 * LDH];
    __shared__ unsigned short Ls[64 * LDH];
    __shared__ float Gs[64 * 65];
    __shared__ const float* rowp[64];
    __shared__ float wj64[64];

    int b = blockIdx.x, tid = threadIdx.x;
    int wave = tid >> 6, lane = tid & 63, quad = lane >> 4, l16 = lane & 15;
    int rs = (wave >> 1) * 16;        // row strip
    int cpair = (wave & 1) * 2;       // first of 2 col tiles

    if (tid < 64) {
        const float* p = (tid == 0) ? feat + (size_t)indexes[b] * Dd
                                    : clu_mean + (size_t)labels[knn[b * 64 + tid]] * Dd;
        rowp[tid] = p;
        wj64[tid] = expf(all_pred[(b * 64 + tid) * 2 + 1]);
    }
    __syncthreads();

    f32x4 acc[2];
#pragma unroll
    for (int j = 0; j < 2; j++) acc[j] = (f32x4){0.f, 0.f, 0.f, 0.f};

    for (int ch = 0; ch < 8; ch++) {
        int d0 = ch * 256;
        __syncthreads();
#pragma unroll
        for (int q = 0; q < 8; q++) {
            int e4 = tid + q * 512;
            int row = e4 >> 6;
            int c4 = (e4 & 63) * 4;
            float4 v = *(const float4*)(rowp[row] + d0 + c4);
            ushort4 h, l;
            h.x = f2bf(v.x); l.x = f2bf(v.x - bf2f(h.x));
            h.y = f2bf(v.y); l.y = f2bf(v.y - bf2f(h.y));
            h.z = f2bf(v.z); l.z = f2bf(v.z - bf2f(h.z));
            h.w = f2bf(v.w); l.w = f2bf(v.w - bf2f(h.w));
            *(ushort4*)&Hs[row * LDH + c4] = h;
            *(ushort4*)&Ls[row * LDH + c4] = l;
        }
        __syncthreads();
#pragma unroll
        for (int ks = 0; ks < 8; ks++) {
            int kk = ks * 32 + quad * 8;
            bf16x8 ah = *(const bf16x8*)&Hs[(rs + l16) * LDH + kk];
            bf16x8 al = *(const bf16x8*)&Ls[(rs + l16) * LDH + kk];
#pragma unroll
            for (int j = 0; j < 2; j++) {
                int jg = cpair + j;
                bf16x8 bh = *(const bf16x8*)&Hs[(jg * 16 + l16) * LDH + kk];
                bf16x8 bl = *(const bf16x8*)&Ls[(jg * 16 + l16) * LDH + kk];
                acc[j] = __builtin_amdgcn_mfma_f32_16x16x32_bf16(ah, bh, acc[j], 0, 0, 0);
                acc[j] = __builtin_amdgcn_mfma_f32_16x16x32_bf16(ah, bl, acc[j], 0, 0, 0);
                acc[j] = __builtin_amdgcn_mfma_f32_16x16x32_bf16(al, bh, acc[j], 0, 0, 0);
            }
        }
    }
    __syncthreads();
#pragma unroll
    for (int j = 0; j < 2; j++)
#pragma unroll
        for (int r = 0; r < 4; r++)
            Gs[(rs + quad * 4 + r) * 65 + (cpair + j) * 16 + l16] = acc[j][r];
    __syncthreads();
    // parallel row softmax: 64 rows x 8 lanes, 8 cols per lane
    {
        int r = tid >> 3, s = tid & 7;
        float e[8];
        float mx = -1e30f;
#pragma unroll
        for (int c8 = 0; c8 < 8; c8++) {
            int c = s * 8 + c8;
            float v = Gs[r * 65 + c] * wj64[c];
            e[c8] = v;
            mx = fmaxf(mx, v);
        }
        mx = fmaxf(mx, __shfl_xor(mx, 1, 64));
        mx = fmaxf(mx, __shfl_xor(mx, 2, 64));
        mx = fmaxf(mx, __shfl_xor(mx, 4, 64));
        float sum = 0.f;
#pragma unroll
        for (int c8 = 0; c8 < 8; c8++) {
            e[c8] = expf(e[c8] - mx);
            sum += e[c8];
        }
        sum += __shfl_xor(sum, 1, 64);
        sum += __shfl_xor(sum, 2, 64);
        sum += __shfl_xor(sum, 4, 64);
        float inv = 1.f / sum;
        float* Arow = Abuf + ((size_t)b * 64 + r) * 64;
#pragma unroll
        for (int c8 = 0; c8 < 8; c8++) Arow[s * 8 + c8] = e[c8] * inv;
    }
}

// ---------------- merged weight repack ----------------
__device__ __forceinline__ void pack_item(const float* __restrict__ W,
                                          unsigned short* __restrict__ Bp,
                                          int K, int Nhalf, int split, int idx) {
    int Ntot = split ? 2 * Nhalf : Nhalf;
    int kb = idx / Ntot;
    int n = idx - kb * Ntot;
    float v[8];
#pragma unroll
    for (int j = 0; j < 8; j++) {
        int k = kb * 8 + j;
        if (split)
            v[j] = (n < Nhalf) ? W[(size_t)k * Nhalf + n]
                               : W[(size_t)(K + k) * Nhalf + (n - Nhalf)];
        else
            v[j] = W[(size_t)k * Nhalf + n];
    }
    ushort4 lo, hi;
    lo.x = f2bf(v[0]); lo.y = f2bf(v[1]); lo.z = f2bf(v[2]); lo.w = f2bf(v[3]);
    hi.x = f2bf(v[4]); hi.y = f2bf(v[5]); hi.z = f2bf(v[6]); hi.w = f2bf(v[7]);
    *(ushort4*)&Bp[(size_t)idx * 8] = lo;
    *(ushort4*)&Bp[(size_t)idx * 8 + 4] = hi;
}

// blocks [0,1024): W1 split-pack; [1024,1152): W2 straight (K=1024); [1152,1184): Wc1
__global__ __launch_bounds__(256) void k_pack_all(
    const float* __restrict__ W1, const float* __restrict__ W2,
    const float* __restrict__ Wc1, unsigned short* __restrict__ Bp1,
    unsigned short* __restrict__ Bp2, unsigned short* __restrict__ Bpc) {
    int blk = blockIdx.x;
    int tid = threadIdx.x;
    if (blk < 1024) {
        pack_item(W1, Bp1, Dd, NHID, 1, blk * 256 + tid);
    } else if (blk < 1024 + 128) {
        pack_item(W2, Bp2, 2 * NHID, H2d, 0, (blk - 1024) * 256 + tid);
    } else {
        pack_item(Wc1, Bpc, H2d, H2d, 0, (blk - 1152) * 256 + tid);
    }
}

// ---------------- bf16 MFMA GEMM (m97 structure), 3 epilogues ----------------
// EPI 0: f32 store.  EPI 2: relu(v+bias) -> bf16 store.
// EPI 3: prelu(v+bias), dot with Wc2 -> atomicAdd logits (no C store).
template <int EPI>
__global__ __launch_bounds__(256) void gemm_bf16_mfma(
    const unsigned short* __restrict__ A, const unsigned short* __restrict__ Bp,
    void* __restrict__ Cout, int M, int K, int N,
    const float* __restrict__ bias, const float* __restrict__ pre_a,
    const float* __restrict__ wc2, float* __restrict__ lbuf) {
    __shared__ unsigned short Asm[128 * 32];
    __shared__ unsigned short Bsm[4 * 128 * 8];
    int tid = threadIdx.x;
    int wave = tid >> 6, lane = tid & 63;
    int quad = lane >> 4, l16 = lane & 15;
    int m0 = blockIdx.y * 128, n0 = blockIdx.x * 128;
    int wm = (wave >> 1) * 64, wn = (wave & 1) * 64;

    f32x4 acc[4][4];
#pragma unroll
    for (int i = 0; i < 4; i++)
#pragma unroll
        for (int j = 0; j < 4; j++) acc[i][j] = (f32x4){0.f, 0.f, 0.f, 0.f};

    int ia0 = wave * 2, ia1 = wave * 2 + 1;
    const unsigned short* gA0 = A + (size_t)(m0 + ia0 * 16 + (lane >> 2)) * K + (lane & 3) * 8;
    const unsigned short* gA1 = gA0 + (size_t)16 * K;
    const unsigned short* gB0 = Bp + (size_t)(n0 + lane) * 8 + (size_t)wave * N * 8;

    for (int k0 = 0; k0 < K; k0 += 32) {
        __syncthreads();
        size_t bko = (size_t)(k0 >> 3) * N * 8;
        __builtin_amdgcn_global_load_lds(
            (const __attribute__((address_space(1))) void*)(gA0 + k0),
            (__attribute__((address_space(3))) void*)(Asm + ia0 * 512), 16, 0, 0);
        __builtin_amdgcn_global_load_lds(
            (const __attribute__((address_space(1))) void*)(gA1 + k0),
            (__attribute__((address_space(3))) void*)(Asm + ia1 * 512), 16, 0, 0);
        __builtin_amdgcn_global_load_lds(
            (const __attribute__((address_space(1))) void*)(gB0 + bko),
            (__attribute__((address_space(3))) void*)(Bsm + wave * 1024), 16, 0, 0);
        __builtin_amdgcn_global_load_lds(
            (const __attribute__((address_space(1))) void*)(gB0 + bko + 512),
            (__attribute__((address_space(3))) void*)(Bsm + wave * 1024 + 512), 16, 0, 0);
        __syncthreads();

        bf16x8 a[4], b[4];
#pragma unroll
        for (int i = 0; i < 4; i++)
            a[i] = *(const bf16x8*)&Asm[(wm + i * 16 + l16) * 32 + quad * 8];
#pragma unroll
        for (int j = 0; j < 4; j++)
            b[j] = *(const bf16x8*)&Bsm[quad * 1024 + (wn + j * 16 + l16) * 8];
#pragma unroll
        for (int i = 0; i < 4; i++)
#pragma unroll
            for (int j = 0; j < 4; j++)
                acc[i][j] = __builtin_amdgcn_mfma_f32_16x16x32_bf16(
                    a[i], b[j], acc[i][j], 0, 0, 0);
    }

    if (EPI == 0) {
        float* C = (float*)Cout;
#pragma unroll
        for (int i = 0; i < 4; i++)
#pragma unroll
            for (int j = 0; j < 4; j++) {
                int col = n0 + wn + j * 16 + l16;
#pragma unroll
                for (int r = 0; r < 4; r++) {
                    int row = m0 + wm + i * 16 + quad * 4 + r;
                    C[(size_t)row * N + col] = acc[i][j][r];
                }
            }
    } else if (EPI == 2) {
        unsigned short* C = (unsigned short*)Cout;
#pragma unroll
        for (int i = 0; i < 4; i++)
#pragma unroll
            for (int j = 0; j < 4; j++) {
                int col = n0 + wn + j * 16 + l16;
                float bcol = bias[col];
#pragma unroll
                for (int r = 0; r < 4; r++) {
                    int row = m0 + wm + i * 16 + quad * 4 + r;
                    float v = acc[i][j][r] + bcol;
                    v = fmaxf(v, 0.f);
                    C[(size_t)row * N + col] = f2bf(v);
                }
            }
    } else {  // EPI == 3: prelu + logit dot, reduce across l16, atomicAdd
#pragma unroll
        for (int i = 0; i < 4; i++) {
#pragma unroll
            for (int r = 0; r < 4; r++) {
                float l0 = 0.f, l1 = 0.f;
#pragma unroll
                for (int j = 0; j < 4; j++) {
                    int col = n0 + wn + j * 16 + l16;
                    float v = acc[i][j][r] + bias[col];
                    v = (v >= 0.f) ? v : pre_a[col] * v;
                    l0 += v * wc2[2 * col];
                    l1 += v * wc2[2 * col + 1];
                }
#pragma unroll
                for (int mm = 1; mm < 16; mm <<= 1) {
                    l0 += __shfl_xor(l0, mm, 64);
                    l1 += __shfl_xor(l1, mm, 64);
                }
                if (l16 == 0) {
                    int row = m0 + wm + i * 16 + quad * 4 + r;
                    atomicAdd(&lbuf[2 * row], l0);
                    atomicAdd(&lbuf[2 * row + 1], l1);
                }
            }
        }
    }
}

// ---------------- fused layer-1: x1 = relu((Pa-Qa) + A@(Pb-Qb) + b1), y1 = A@x1 ----------------
// MFMA formulation. grid (Bq, 2): half hf handles col windows [hf*4, hf*4+4) of 64.
__global__ __launch_bounds__(256) void k_gcn1(
    const float* __restrict__ P, const float* __restrict__ Abuf,
    const int* __restrict__ labels, const int* __restrict__ knn,
    const float* __restrict__ bias, unsigned short* __restrict__ xy1) {
    __shared__ unsigned short Ah[64 * LDA1], Al[64 * LDA1];   // adjacency hi/lo [k'][j]
    __shared__ unsigned short Xh[64 * LDA1], Xl[64 * LDA1];   // D transposed [c][j]
    __shared__ unsigned short Tt[64 * LDA1];                  // x1 tile transposed [c][k]
    __shared__ int rowid[64];

    int b = blockIdx.x, hf = blockIdx.y, tid = threadIdx.x;
    int wave = tid >> 6, lane = tid & 63, quad = lane >> 4, l16 = lane & 15;

    if (tid < 64)
        rowid[tid] = (tid == 0) ? (PIVROW + b) : labels[knn[b * 64 + tid]];

    // stage adjacency hi/lo (row-major [k'][j])
    const float* Ab = Abuf + (size_t)b * 64 * 64;
#pragma unroll
    for (int q = 0; q < 4; q++) {
        int e4 = tid + q * 256;
        int row = e4 >> 4;
        int c4 = (e4 & 15) * 4;
        float4 v = *(const float4*)(Ab + row * 64 + c4);
        ushort4 h, l;
        h.x = f2bf(v.x); l.x = f2bf(v.x - bf2f(h.x));
        h.y = f2bf(v.y); l.y = f2bf(v.y - bf2f(h.y));
        h.z = f2bf(v.z); l.z = f2bf(v.z - bf2f(h.z));
        h.w = f2bf(v.w); l.w = f2bf(v.w - bf2f(h.w));
        *(ushort4*)&Ah[row * LDA1 + c4] = h;
        *(ushort4*)&Al[row * LDA1 + c4] = l;
    }

    const float* Q = P + (size_t)(PIVROW + b) * 1024;
    unsigned short* xout = xy1 + (size_t)b * 64 * 1024;

    for (int w = hf * 4; w < hf * 4 + 4; w++) {
        int w0 = w * 64;
        __syncthreads();   // A/rowid ready (iter 0); Tt free (later iters)
        // stage D[j][c] = Pb[rowid[j]][c] - Qb[c], transposed hi/lo: X*[c*LDA1 + j]
#pragma unroll
        for (int q = 0; q < 4; q++) {
            int e4 = tid + q * 256;
            int j = e4 >> 4;
            int c4 = (e4 & 15) * 4;
            float4 v = *(const float4*)(P + (size_t)rowid[j] * 1024 + 512 + w0 + c4);
            float4 qv = *(const float4*)(Q + 512 + w0 + c4);
            v.x -= qv.x; v.y -= qv.y; v.z -= qv.z; v.w -= qv.w;
            unsigned short h;
            h = f2bf(v.x); Xh[(c4 + 0) * LDA1 + j] = h; Xl[(c4 + 0) * LDA1 + j] = f2bf(v.x - bf2f(h));
            h = f2bf(v.y); Xh[(c4 + 1) * LDA1 + j] = h; Xl[(c4 + 1) * LDA1 + j] = f2bf(v.y - bf2f(h));
            h = f2bf(v.z); Xh[(c4 + 2) * LDA1 + j] = h; Xl[(c4 + 2) * LDA1 + j] = f2bf(v.z - bf2f(h));
            h = f2bf(v.w); Xh[(c4 + 3) * LDA1 + j] = h; Xl[(c4 + 3) * LDA1 + j] = f2bf(v.w - bf2f(h));
        }
        __syncthreads();
        // mix1: acc = A @ D (3-pass hi/lo)
        f32x4 acc[4];
#pragma unroll
        for (int t = 0; t < 4; t++) acc[t] = (f32x4){0.f, 0.f, 0.f, 0.f};
#pragma unroll
        for (int ks = 0; ks < 2; ks++) {
            int j0 = ks * 32 + quad * 8;
            bf16x8 ah = *(const bf16x8*)&Ah[(wave * 16 + l16) * LDA1 + j0];
            bf16x8 al = *(const bf16x8*)&Al[(wave * 16 + l16) * LDA1 + j0];
#pragma unroll
            for (int t = 0; t < 4; t++) {
                bf16x8 bh = *(const bf16x8*)&Xh[(t * 16 + l16) * LDA1 + j0];
                bf16x8 bl = *(const bf16x8*)&Xl[(t * 16 + l16) * LDA1 + j0];
                acc[t] = __builtin_amdgcn_mfma_f32_16x16x32_bf16(ah, bh, acc[t], 0, 0, 0);
                acc[t] = __builtin_amdgcn_mfma_f32_16x16x32_bf16(ah, bl, acc[t], 0, 0, 0);
                acc[t] = __builtin_amdgcn_mfma_f32_16x16x32_bf16(al, bh, acc[t], 0, 0, 0);
            }
        }
        // epilogue1: x1 = relu(acc + (Pa-Qa) + b1); write bf16 global + Tt LDS
#pragma unroll
        for (int t = 0; t < 4; t++) {
            int cl = t * 16 + l16;      // local col
            int c = w0 + cl;            // global col (< 512)
            float bb = bias[c];
            float qa = Q[c];
#pragma unroll
            for (int r = 0; r < 4; r++) {
                int k = wave * 16 + quad * 4 + r;
                float ua = P[(size_t)rowid[k] * 1024 + c] - qa;
                float v = fmaxf(acc[t][r] + ua + bb, 0.f);
                unsigned short hv = f2bf(v);
                xout[(size_t)k * 1024 + c] = hv;
                Tt[cl * LDA1 + k] = hv;
            }
        }
        __syncthreads();
        // mix2: acc2 = A @ bf16(x1) (2-pass hi/lo on A)
        f32x4 acc2[4];
#pragma unroll
        for (int t = 0; t < 4; t++) acc2[t] = (f32x4){0.f, 0.f, 0.f, 0.f};
#pragma unroll
        for (int ks = 0; ks < 2; ks++) {
            int j0 = ks * 32 + quad * 8;
            bf16x8 ah = *(const bf16x8*)&Ah[(wave * 16 + l16) * LDA1 + j0];
            bf16x8 al = *(const bf16x8*)&Al[(wave * 16 + l16) * LDA1 + j0];
#pragma unroll
            for (int t = 0; t < 4; t++) {
                bf16x8 bh = *(const bf16x8*)&Tt[(t * 16 + l16) * LDA1 + j0];
                acc2[t] = __builtin_amdgcn_mfma_f32_16x16x32_bf16(ah, bh, acc2[t], 0, 0, 0);
                acc2[t] = __builtin_amdgcn_mfma_f32_16x16x32_bf16(al, bh, acc2[t], 0, 0, 0);
            }
        }
        // epilogue2: y1 -> xy1 upper half
#pragma unroll
        for (int t = 0; t < 4; t++) {
            int c = 512 + w0 + t * 16 + l16;
#pragma unroll
            for (int r = 0; r < 4; r++) {
                int k = wave * 16 + quad * 4 + r;
                xout[(size_t)k * 1024 + c] = f2bf(acc2[t][r]);
            }
        }
    }
}

// ---------------- 2-class softmax from accumulated logits ----------------
__global__ void k_soft2(const float* __restrict__ lbuf, const float* __restrict__ bc2,
                        float* __restrict__ pred) {
    int m = blockIdx.x * 256 + threadIdx.x;
    if (m < Bq * Kn) {
        float L0 = lbuf[2 * m] + bc2[0];
        float L1 = lbuf[2 * m + 1] + bc2[1];
        float mx = fmaxf(L0, L1);
        float e0 = expf(L0 - mx), e1 = expf(L1 - mx);
        float inv = 1.f / (e0 + e1);
        pred[2 * m] = e0 * inv;
        pred[2 * m + 1] = e1 * inv;
    }
}

// ---------------- launch ----------------
extern "C" void kernel_launch(void* const* d_in, const int* in_sizes, int n_in,
                              void* d_out, int out_size, void* d_ws, size_t ws_size,
                              hipStream_t stream) {
    const int* indexes = (const int*)d_in[0];
    const float* features = (const float*)d_in[1];
    const int* labels = (const int*)d_in[2];
    const int* knn = (const int*)d_in[5];
    const float* all_pred = (const float*)d_in[6];
    const float* W1 = (const float*)d_in[7];
    const float* b1 = (const float*)d_in[8];
    const float* W2 = (const float*)d_in[9];
    const float* b2 = (const float*)d_in[10];
    const float* Wc1 = (const float*)d_in[11];
    const float* bc1 = (const float*)d_in[12];
    const float* pre_a = (const float*)d_in[13];
    const float* Wc2 = (const float*)d_in[14];
    const float* bc2 = (const float*)d_in[15];
    float* out = (float*)d_out;

    char* w = (char*)d_ws;
    size_t o = 0;
    auto carve = [&](size_t bytes) -> char* {
        char* p = w + o;
        o += (bytes + 255) & ~(size_t)255;
        return p;
    };
    int* cnt = (int*)carve((size_t)Cc * 4);
    int* off = (int*)carve((size_t)Cc * 4);
    int* pos = (int*)carve((size_t)Cc * 4);
    int* total = (int*)carve(4);
    int* rowidx = (int*)carve((size_t)Nn * 4);
    float* clu_mean = (float*)carve((size_t)Cc * Dd * 4);                       // 41 MB
    unsigned short* PA = (unsigned short*)carve((size_t)MP * Dd * 2);           // 22 MB
    float* Pout = (float*)carve((size_t)MP * 2 * NHID * 4);                     // 22 MB
    float* Abuf = (float*)carve((size_t)Bq * Kn * Kn * 4);                      // 4.2 MB
    unsigned short* Bp1 = (unsigned short*)carve((size_t)(Dd / 8) * 1024 * 8 * 2);   // 4.2 MB
    unsigned short* xy1 = (unsigned short*)carve((size_t)Bq * Kn * 1024 * 2);   // 33.6 MB
    unsigned short* Bp2 = (unsigned short*)carve((size_t)(2 * NHID / 8) * H2d * 8 * 2);  // 0.52 MB
    unsigned short* x2 = (unsigned short*)carve((size_t)Bq * Kn * H2d * 2);     // 8.4 MB
    unsigned short* Bpc = (unsigned short*)carve((size_t)(H2d / 8) * 256 * 8 * 2);   // 0.13 MB
    float* lbuf = (float*)carve((size_t)Bq * Kn * 2 * 4);                       // 0.13 MB

    float* simm_out = out + (size_t)Bq * Kn * 2;

    // 1) zero: cnt, PA pad rows, lbuf, alloc counter  (one kernel)
    {
        int nPad = (PIVROW - Cc) * Dd / 2;   // pad shorts -> ints
        int nLb = Bq * Kn * 2;               // floats -> ints (0 bits == 0.0f)
        int ntot = Cc + nPad + nLb + 1;
        k_zero_multi<<<(ntot + 255) / 256, 256, 0, stream>>>(
            cnt, Cc, (int*)(PA + (size_t)Cc * Dd), nPad, (int*)lbuf, nLb, total, 1);
    }
    k_count<<<(Nn + 255) / 256, 256, 0, stream>>>(labels, cnt, Nn);
    k_alloc<<<(Cc + 255) / 256, 256, 0, stream>>>(cnt, off, pos, total, Cc);
    k_scatter<<<(Nn + 255) / 256, 256, 0, stream>>>(labels, pos, rowidx, Nn);

    // 2) cluster means + simm + normalized means; pivot rows appended to grid
    k_meansimm<<<Cc + Bq, 256, 0, stream>>>(features, rowidx, off, cnt, indexes,
                                            clu_mean, simm_out, PA);

    // 3) per-batch adjacency (MFMA hi/lo gram), 512 threads
    k_build_ax<<<Bq, 512, 0, stream>>>(features, clu_mean, labels, indexes, knn,
                                       all_pred, Abuf);

    // 3b) all weight packs in one launch
    k_pack_all<<<1184, 256, 0, stream>>>(W1, W2, Wc1, Bp1, Bp2, Bpc);

    // 4) Pout = PA @ [W1a | W1b]  (M=5376, K=2048, N=1024)
    {
        dim3 g(1024 / 128, MP / 128);
        gemm_bf16_mfma<0><<<g, 256, 0, stream>>>(PA, Bp1, Pout, MP, Dd, 1024,
                                                 nullptr, nullptr, nullptr, nullptr);
    }
    // 5) fused layer-1: x1 + y1 -> xy1 (MFMA)
    {
        dim3 g(Bq, 2);
        k_gcn1<<<g, 256, 0, stream>>>(Pout, Abuf, labels, knn, b1, xy1);
    }
    // 6) x2 = relu([x1|y1] @ W2 + b2)  (M=16384, K=1024, N=256) -> bf16
    {
        dim3 g(H2d / 128, (Bq * Kn) / 128);
        gemm_bf16_mfma<2><<<g, 256, 0, stream>>>(xy1, Bp2, x2, Bq * Kn, 1024, H2d,
                                                 b2, nullptr, nullptr, nullptr);
    }
    // 7) logits = prelu(x2 @ Wc1 + bc1) @ Wc2, accumulated into lbuf (no h buffer)
    {
        dim3 g(H2d / 128, (Bq * Kn) / 128);
        gemm_bf16_mfma<3><<<g, 256, 0, stream>>>(x2, Bpc, nullptr, Bq * Kn, H2d, H2d,
                                                 bc1, pre_a, Wc2, lbuf);
    }
    // 8) softmax -> pred
    k_soft2<<<(Bq * Kn + 255) / 256, 256, 0, stream>>>(lbuf, bc2, out);

    (void)in_sizes; (void)n_in; (void)out_size; (void)ws_size;
}

// Round 4
// 762.514 us; speedup vs baseline: 1.1890x; 1.0466x over previous
//
#include <hip/hip_runtime.h>
#include <math.h>

#define Bq 256
#define Kn 64
#define Dd 2048
#define Nn 50000
#define Cc 5000
#define NHID 512
#define H2d 256
#define LDH 264   // padded LDS row stride (shorts) for gram staging
#define MP 5376   // padded P-matrix rows: 5000 cn + 120 pad + 256 pivots
#define PIVROW 5120
#define LDA1 72   // LDS row stride (shorts) for gcn1 tiles

typedef __attribute__((ext_vector_type(8))) __bf16 bf16x8;
typedef __attribute__((ext_vector_type(4))) float f32x4;

__device__ __forceinline__ unsigned short f2bf(float f) {
    union { float f; unsigned int u; } v;
    v.f = f;
    unsigned int u = v.u;
    unsigned int r = (u + 0x7fff + ((u >> 16) & 1)) >> 16;   // RNE
    return (unsigned short)r;
}
__device__ __forceinline__ float bf2f(unsigned short h) {
    union { unsigned int u; float f; } v;
    v.u = ((unsigned int)h) << 16;
    return v.f;
}

// ---------------- merged zero kernel ----------------
__global__ void k_zero_multi(int* __restrict__ p0, int n0,
                             int* __restrict__ p1, int n1,
                             int* __restrict__ p2, int n2,
                             int* __restrict__ p3, int n3) {
    int i = blockIdx.x * 256 + threadIdx.x;
    if (i < n0) { p0[i] = 0; return; }
    i -= n0;
    if (i < n1) { p1[i] = 0; return; }
    i -= n1;
    if (i < n2) { p2[i] = 0; return; }
    i -= n2;
    if (i < n3) p3[i] = 0;
}

__global__ void k_count(const int* __restrict__ labels, int* __restrict__ cnt, int n) {
    int i = blockIdx.x * 256 + threadIdx.x;
    if (i < n) atomicAdd(&cnt[labels[i]], 1);
}

// atomic segment allocator: contiguous (unordered) cluster offsets
__global__ void k_alloc(const int* __restrict__ cnt, int* __restrict__ off,
                        int* __restrict__ pos, int* __restrict__ total, int C) {
    int c = blockIdx.x * 256 + threadIdx.x;
    if (c < C) {
        int o = atomicAdd(total, cnt[c]);
        off[c] = o;
        pos[c] = o;
    }
}

__global__ void k_scatter(const int* __restrict__ labels, int* __restrict__ pos,
                          int* __restrict__ rowidx, int n) {
    int i = blockIdx.x * 256 + threadIdx.x;
    if (i < n) {
        int p = atomicAdd(&pos[labels[i]], 1);
        rowidx[p] = i;
    }
}

// ---------------- cluster mean + simm + normalized-mean (bf16); pivot rows merged ----------------
__global__ __launch_bounds__(256) void k_meansimm(
    const float* __restrict__ feat, const int* __restrict__ rowidx,
    const int* __restrict__ off, const int* __restrict__ cnt,
    const int* __restrict__ indexes,
    float* __restrict__ clu_mean, float* __restrict__ simm,
    unsigned short* __restrict__ PA) {
    int c = blockIdx.x;
    int t = threadIdx.x;
    __shared__ float red[256];

    if (c >= Cc) {
        // pivot path: normalized raw feature row -> PA[PIVROW + b]
        int b = c - Cc;
        const float* row = feat + (size_t)indexes[b] * Dd;
        float4 v0 = *(const float4*)(row + t * 4);
        float4 v1 = *(const float4*)(row + 1024 + t * 4);
        float ss = v0.x * v0.x + v0.y * v0.y + v0.z * v0.z + v0.w * v0.w +
                   v1.x * v1.x + v1.y * v1.y + v1.z * v1.z + v1.w * v1.w;
        red[t] = ss;
        __syncthreads();
        for (int s2 = 128; s2 > 0; s2 >>= 1) {
            if (t < s2) red[t] += red[t + s2];
            __syncthreads();
        }
        float tot = red[0];
        float rnn = (tot > 0.f) ? rsqrtf(tot) : 0.f;
        ushort4 c0, c1;
        c0.x = f2bf(v0.x * rnn); c0.y = f2bf(v0.y * rnn);
        c0.z = f2bf(v0.z * rnn); c0.w = f2bf(v0.w * rnn);
        c1.x = f2bf(v1.x * rnn); c1.y = f2bf(v1.y * rnn);
        c1.z = f2bf(v1.z * rnn); c1.w = f2bf(v1.w * rnn);
        unsigned short* cr = PA + (size_t)(PIVROW + b) * Dd;
        *(ushort4*)(cr + t * 4) = c0;
        *(ushort4*)(cr + 1024 + t * 4) = c1;
        return;
    }

    int n = cnt[c], st = off[c];
    float4 a0 = {0.f, 0.f, 0.f, 0.f}, a1 = {0.f, 0.f, 0.f, 0.f};
    for (int r = 0; r < n; r++) {
        const float* row = feat + (size_t)rowidx[st + r] * Dd;
        float4 v0 = *(const float4*)(row + t * 4);
        float4 v1 = *(const float4*)(row + 1024 + t * 4);
        a0.x += v0.x; a0.y += v0.y; a0.z += v0.z; a0.w += v0.w;
        a1.x += v1.x; a1.y += v1.y; a1.z += v1.z; a1.w += v1.w;
    }
    float sc = 1.f / (float)(n > 1 ? n : 1);
    a0.x *= sc; a0.y *= sc; a0.z *= sc; a0.w *= sc;
    a1.x *= sc; a1.y *= sc; a1.z *= sc; a1.w *= sc;
    float* outr = clu_mean + (size_t)c * Dd;
    *(float4*)(outr + t * 4) = a0;
    *(float4*)(outr + 1024 + t * 4) = a1;
    float ss = a0.x * a0.x + a0.y * a0.y + a0.z * a0.z + a0.w * a0.w +
               a1.x * a1.x + a1.y * a1.y + a1.z * a1.z + a1.w * a1.w;
    red[t] = ss;
    __syncthreads();
    for (int s2 = 128; s2 > 0; s2 >>= 1) {
        if (t < s2) red[t] += red[t + s2];
        __syncthreads();
    }
    if (t == 0) simm[c] = red[0];
    float tot = red[0];
    float rnn = (tot > 0.f) ? rsqrtf(tot) : 0.f;
    ushort4 c0, c1;
    c0.x = f2bf(a0.x * rnn); c0.y = f2bf(a0.y * rnn);
    c0.z = f2bf(a0.z * rnn); c0.w = f2bf(a0.w * rnn);
    c1.x = f2bf(a1.x * rnn); c1.y = f2bf(a1.y * rnn);
    c1.z = f2bf(a1.z * rnn); c1.w = f2bf(a1.w * rnn);
    unsigned short* cr = PA + (size_t)c * Dd;
    *(ushort4*)(cr + t * 4) = c0;
    *(ushort4*)(cr + 1024 + t * 4) = c1;
}

// ---------------- per-batch: A (MFMA hi/lo gram), 512 threads ----------------
__global__ __launch_bounds__(512) void k_build_ax(
    const float* __restrict__ feat, const float* __restrict__ clu_mean,
    const int* __restrict__ labels, const int* __restrict__ indexes,
    const int* __restrict__ knn, const float* __restrict__ all_pred,
    float* __restrict__ Abuf) {
    __shared__ unsigned short Hs[64 * LDH];
    __shared__ unsigned short Ls[64 * LDH];
    __shared__ float Gs[64 * 65];
    __shared__ const float* rowp[64];
    __shared__ float wj64[64];

    int b = blockIdx.x, tid = threadIdx.x;
    int wave = tid >> 6, lane = tid & 63, quad = lane >> 4, l16 = lane & 15;
    int rs = (wave >> 1) * 16;        // row strip
    int cpair = (wave & 1) * 2;       // first of 2 col tiles

    if (tid < 64) {
        const float* p = (tid == 0) ? feat + (size_t)indexes[b] * Dd
                                    : clu_mean + (size_t)labels[knn[b * 64 + tid]] * Dd;
        rowp[tid] = p;
        wj64[tid] = expf(all_pred[(b * 64 + tid) * 2 + 1]);
    }
    __syncthreads();

    f32x4 acc[2];
#pragma unroll
    for (int j = 0; j < 2; j++) acc[j] = (f32x4){0.f, 0.f, 0.f, 0.f};

    for (int ch = 0; ch < 8; ch++) {
        int d0 = ch * 256;
        __syncthreads();
#pragma unroll
        for (int q = 0; q < 8; q++) {
            int e4 = tid + q * 512;
            int row = e4 >> 6;
            int c4 = (e4 & 63) * 4;
            float4 v = *(const float4*)(rowp[row] + d0 + c4);
            ushort4 h, l;
            h.x = f2bf(v.x); l.x = f2bf(v.x - bf2f(h.x));
            h.y = f2bf(v.y); l.y = f2bf(v.y - bf2f(h.y));
            h.z = f2bf(v.z); l.z = f2bf(v.z - bf2f(h.z));
            h.w = f2bf(v.w); l.w = f2bf(v.w - bf2f(h.w));
            *(ushort4*)&Hs[row * LDH + c4] = h;
            *(ushort4*)&Ls[row * LDH + c4] = l;
        }
        __syncthreads();
#pragma unroll
        for (int ks = 0; ks < 8; ks++) {
            int kk = ks * 32 + quad * 8;
            bf16x8 ah = *(const bf16x8*)&Hs[(rs + l16) * LDH + kk];
            bf16x8 al = *(const bf16x8*)&Ls[(rs + l16) * LDH + kk];
#pragma unroll
            for (int j = 0; j < 2; j++) {
                int jg = cpair + j;
                bf16x8 bh = *(const bf16x8*)&Hs[(jg * 16 + l16) * LDH + kk];
                bf16x8 bl = *(const bf16x8*)&Ls[(jg * 16 + l16) * LDH + kk];
                acc[j] = __builtin_amdgcn_mfma_f32_16x16x32_bf16(ah, bh, acc[j], 0, 0, 0);
                acc[j] = __builtin_amdgcn_mfma_f32_16x16x32_bf16(ah, bl, acc[j], 0, 0, 0);
                acc[j] = __builtin_amdgcn_mfma_f32_16x16x32_bf16(al, bh, acc[j], 0, 0, 0);
            }
        }
    }
    __syncthreads();
#pragma unroll
    for (int j = 0; j < 2; j++)
#pragma unroll
        for (int r = 0; r < 4; r++)
            Gs[(rs + quad * 4 + r) * 65 + (cpair + j) * 16 + l16] = acc[j][r];
    __syncthreads();
    // parallel row softmax: 64 rows x 8 lanes, 8 cols per lane
    {
        int r = tid >> 3, s = tid & 7;
        float e[8];
        float mx = -1e30f;
#pragma unroll
        for (int c8 = 0; c8 < 8; c8++) {
            int c = s * 8 + c8;
            float v = Gs[r * 65 + c] * wj64[c];
            e[c8] = v;
            mx = fmaxf(mx, v);
        }
        mx = fmaxf(mx, __shfl_xor(mx, 1, 64));
        mx = fmaxf(mx, __shfl_xor(mx, 2, 64));
        mx = fmaxf(mx, __shfl_xor(mx, 4, 64));
        float sum = 0.f;
#pragma unroll
        for (int c8 = 0; c8 < 8; c8++) {
            e[c8] = expf(e[c8] - mx);
            sum += e[c8];
        }
        sum += __shfl_xor(sum, 1, 64);
        sum += __shfl_xor(sum, 2, 64);
        sum += __shfl_xor(sum, 4, 64);
        float inv = 1.f / sum;
        float* Arow = Abuf + ((size_t)b * 64 + r) * 64;
#pragma unroll
        for (int c8 = 0; c8 < 8; c8++) Arow[s * 8 + c8] = e[c8] * inv;
    }
}

// ---------------- merged weight repack ----------------
__device__ __forceinline__ void pack_item(const float* __restrict__ W,
                                          unsigned short* __restrict__ Bp,
                                          int K, int Nhalf, int split, int idx) {
    int Ntot = split ? 2 * Nhalf : Nhalf;
    int kb = idx / Ntot;
    int n = idx - kb * Ntot;
    float v[8];
#pragma unroll
    for (int j = 0; j < 8; j++) {
        int k = kb * 8 + j;
        if (split)
            v[j] = (n < Nhalf) ? W[(size_t)k * Nhalf + n]
                               : W[(size_t)(K + k) * Nhalf + (n - Nhalf)];
        else
            v[j] = W[(size_t)k * Nhalf + n];
    }
    ushort4 lo, hi;
    lo.x = f2bf(v[0]); lo.y = f2bf(v[1]); lo.z = f2bf(v[2]); lo.w = f2bf(v[3]);
    hi.x = f2bf(v[4]); hi.y = f2bf(v[5]); hi.z = f2bf(v[6]); hi.w = f2bf(v[7]);
    *(ushort4*)&Bp[(size_t)idx * 8] = lo;
    *(ushort4*)&Bp[(size_t)idx * 8 + 4] = hi;
}

// blocks [0,1024): W1 split-pack; [1024,1152): W2 straight (K=1024); [1152,1184): Wc1
__global__ __launch_bounds__(256) void k_pack_all(
    const float* __restrict__ W1, const float* __restrict__ W2,
    const float* __restrict__ Wc1, unsigned short* __restrict__ Bp1,
    unsigned short* __restrict__ Bp2, unsigned short* __restrict__ Bpc) {
    int blk = blockIdx.x;
    int tid = threadIdx.x;
    if (blk < 1024) {
        pack_item(W1, Bp1, Dd, NHID, 1, blk * 256 + tid);
    } else if (blk < 1024 + 128) {
        pack_item(W2, Bp2, 2 * NHID, H2d, 0, (blk - 1024) * 256 + tid);
    } else {
        pack_item(Wc1, Bpc, H2d, H2d, 0, (blk - 1152) * 256 + tid);
    }
}

// ---------------- bf16 MFMA GEMM, BM-templated (64 or 128 rows/block) ----------------
// EPI 0: f32 store.  EPI 2: relu(v+bias) -> bf16 store.
// EPI 3: prelu(v+bias), dot with Wc2 -> atomicAdd logits (no C store).
template <int BM, int EPI>
__global__ __launch_bounds__(256) void gemm_bf16_mfma(
    const unsigned short* __restrict__ A, const unsigned short* __restrict__ Bp,
    void* __restrict__ Cout, int M, int K, int N,
    const float* __restrict__ bias, const float* __restrict__ pre_a,
    const float* __restrict__ wc2, float* __restrict__ lbuf) {
    constexpr int MI = BM / 32;   // a-frags per wave
    __shared__ unsigned short Asm[BM * 32];
    __shared__ unsigned short Bsm[4 * 128 * 8];
    int tid = threadIdx.x;
    int wave = tid >> 6, lane = tid & 63;
    int quad = lane >> 4, l16 = lane & 15;
    int m0 = blockIdx.y * BM, n0 = blockIdx.x * 128;
    int wm = (wave >> 1) * (BM / 2), wn = (wave & 1) * 64;

    f32x4 acc[MI][4];
#pragma unroll
    for (int i = 0; i < MI; i++)
#pragma unroll
        for (int j = 0; j < 4; j++) acc[i][j] = (f32x4){0.f, 0.f, 0.f, 0.f};

    // A staging: BM/16 segments of 16 rows; BM=128 -> 2/wave, BM=64 -> 1/wave
    int ia0 = (BM == 128) ? wave * 2 : wave;
    const unsigned short* gA0 = A + (size_t)(m0 + ia0 * 16 + (lane >> 2)) * K + (lane & 3) * 8;
    const unsigned short* gA1 = gA0 + (size_t)16 * K;   // only used when BM==128
    const unsigned short* gB0 = Bp + (size_t)(n0 + lane) * 8 + (size_t)wave * N * 8;

    for (int k0 = 0; k0 < K; k0 += 32) {
        __syncthreads();
        size_t bko = (size_t)(k0 >> 3) * N * 8;
        __builtin_amdgcn_global_load_lds(
            (const __attribute__((address_space(1))) void*)(gA0 + k0),
            (__attribute__((address_space(3))) void*)(Asm + ia0 * 512), 16, 0, 0);
        if constexpr (BM == 128) {
            __builtin_amdgcn_global_load_lds(
                (const __attribute__((address_space(1))) void*)(gA1 + k0),
                (__attribute__((address_space(3))) void*)(Asm + (ia0 + 1) * 512), 16, 0, 0);
        }
        __builtin_amdgcn_global_load_lds(
            (const __attribute__((address_space(1))) void*)(gB0 + bko),
            (__attribute__((address_space(3))) void*)(Bsm + wave * 1024), 16, 0, 0);
        __builtin_amdgcn_global_load_lds(
            (const __attribute__((address_space(1))) void*)(gB0 + bko + 512),
            (__attribute__((address_space(3))) void*)(Bsm + wave * 1024 + 512), 16, 0, 0);
        __syncthreads();

        bf16x8 a[MI], b[4];
#pragma unroll
        for (int i = 0; i < MI; i++)
            a[i] = *(const bf16x8*)&Asm[(wm + i * 16 + l16) * 32 + quad * 8];
#pragma unroll
        for (int j = 0; j < 4; j++)
            b[j] = *(const bf16x8*)&Bsm[quad * 1024 + (wn + j * 16 + l16) * 8];
#pragma unroll
        for (int i = 0; i < MI; i++)
#pragma unroll
            for (int j = 0; j < 4; j++)
                acc[i][j] = __builtin_amdgcn_mfma_f32_16x16x32_bf16(
                    a[i], b[j], acc[i][j], 0, 0, 0);
    }

    if (EPI == 0) {
        float* C = (float*)Cout;
#pragma unroll
        for (int i = 0; i < MI; i++)
#pragma unroll
            for (int j = 0; j < 4; j++) {
                int col = n0 + wn + j * 16 + l16;
#pragma unroll
                for (int r = 0; r < 4; r++) {
                    int row = m0 + wm + i * 16 + quad * 4 + r;
                    C[(size_t)row * N + col] = acc[i][j][r];
                }
            }
    } else if (EPI == 2) {
        unsigned short* C = (unsigned short*)Cout;
#pragma unroll
        for (int i = 0; i < MI; i++)
#pragma unroll
            for (int j = 0; j < 4; j++) {
                int col = n0 + wn + j * 16 + l16;
                float bcol = bias[col];
#pragma unroll
                for (int r = 0; r < 4; r++) {
                    int row = m0 + wm + i * 16 + quad * 4 + r;
                    float v = acc[i][j][r] + bcol;
                    v = fmaxf(v, 0.f);
                    C[(size_t)row * N + col] = f2bf(v);
                }
            }
    } else {  // EPI == 3: prelu + logit dot, reduce across l16, atomicAdd
#pragma unroll
        for (int i = 0; i < MI; i++) {
#pragma unroll
            for (int r = 0; r < 4; r++) {
                float l0 = 0.f, l1 = 0.f;
#pragma unroll
                for (int j = 0; j < 4; j++) {
                    int col = n0 + wn + j * 16 + l16;
                    float v = acc[i][j][r] + bias[col];
                    v = (v >= 0.f) ? v : pre_a[col] * v;
                    l0 += v * wc2[2 * col];
                    l1 += v * wc2[2 * col + 1];
                }
#pragma unroll
                for (int mm = 1; mm < 16; mm <<= 1) {
                    l0 += __shfl_xor(l0, mm, 64);
                    l1 += __shfl_xor(l1, mm, 64);
                }
                if (l16 == 0) {
                    int row = m0 + wm + i * 16 + quad * 4 + r;
                    atomicAdd(&lbuf[2 * row], l0);
                    atomicAdd(&lbuf[2 * row + 1], l1);
                }
            }
        }
    }
}

// ---------------- fused layer-1: x1 = relu((Pa-Qa) + A@(Pb-Qb) + b1), y1 = A@x1 ----------------
// grid (Bq, 8): block (b, w) handles col window w of 8. Windows are independent.
__global__ __launch_bounds__(256) void k_gcn1(
    const float* __restrict__ P, const float* __restrict__ Abuf,
    const int* __restrict__ labels, const int* __restrict__ knn,
    const float* __restrict__ bias, unsigned short* __restrict__ xy1) {
    __shared__ unsigned short Ah[64 * LDA1], Al[64 * LDA1];   // adjacency hi/lo [k'][j]
    __shared__ unsigned short Xh[64 * LDA1], Xl[64 * LDA1];   // D transposed [c][j]
    __shared__ unsigned short Tt[64 * LDA1];                  // x1 tile transposed [c][k]
    __shared__ int rowid[64];

    int b = blockIdx.x, w = blockIdx.y, tid = threadIdx.x;
    int wave = tid >> 6, lane = tid & 63, quad = lane >> 4, l16 = lane & 15;
    int w0 = w * 64;

    if (tid < 64)
        rowid[tid] = (tid == 0) ? (PIVROW + b) : labels[knn[b * 64 + tid]];

    // stage adjacency hi/lo (row-major [k'][j])
    const float* Ab = Abuf + (size_t)b * 64 * 64;
#pragma unroll
    for (int q = 0; q < 4; q++) {
        int e4 = tid + q * 256;
        int row = e4 >> 4;
        int c4 = (e4 & 15) * 4;
        float4 v = *(const float4*)(Ab + row * 64 + c4);
        ushort4 h, l;
        h.x = f2bf(v.x); l.x = f2bf(v.x - bf2f(h.x));
        h.y = f2bf(v.y); l.y = f2bf(v.y - bf2f(h.y));
        h.z = f2bf(v.z); l.z = f2bf(v.z - bf2f(h.z));
        h.w = f2bf(v.w); l.w = f2bf(v.w - bf2f(h.w));
        *(ushort4*)&Ah[row * LDA1 + c4] = h;
        *(ushort4*)&Al[row * LDA1 + c4] = l;
    }

    const float* Q = P + (size_t)(PIVROW + b) * 1024;
    unsigned short* xout = xy1 + (size_t)b * 64 * 1024;

    // stage D[j][c] = Pb[rowid[j]][c] - Qb[c], transposed hi/lo: X*[c*LDA1 + j]
    // NOTE: rowid written by tid<64 this block; needs the barrier below before use,
    // so the D stage uses knn/labels directly for its row index.
#pragma unroll
    for (int q = 0; q < 4; q++) {
        int e4 = tid + q * 256;
        int j = e4 >> 4;
        int c4 = (e4 & 15) * 4;
        int rid = (j == 0) ? (PIVROW + b) : labels[knn[b * 64 + j]];
        float4 v = *(const float4*)(P + (size_t)rid * 1024 + 512 + w0 + c4);
        float4 qv = *(const float4*)(Q + 512 + w0 + c4);
        v.x -= qv.x; v.y -= qv.y; v.z -= qv.z; v.w -= qv.w;
        unsigned short h;
        h = f2bf(v.x); Xh[(c4 + 0) * LDA1 + j] = h; Xl[(c4 + 0) * LDA1 + j] = f2bf(v.x - bf2f(h));
        h = f2bf(v.y); Xh[(c4 + 1) * LDA1 + j] = h; Xl[(c4 + 1) * LDA1 + j] = f2bf(v.y - bf2f(h));
        h = f2bf(v.z); Xh[(c4 + 2) * LDA1 + j] = h; Xl[(c4 + 2) * LDA1 + j] = f2bf(v.z - bf2f(h));
        h = f2bf(v.w); Xh[(c4 + 3) * LDA1 + j] = h; Xl[(c4 + 3) * LDA1 + j] = f2bf(v.w - bf2f(h));
    }
    __syncthreads();

    // mix1: acc = A @ D (3-pass hi/lo)
    f32x4 acc[4];
#pragma unroll
    for (int t = 0; t < 4; t++) acc[t] = (f32x4){0.f, 0.f, 0.f, 0.f};
#pragma unroll
    for (int ks = 0; ks < 2; ks++) {
        int j0 = ks * 32 + quad * 8;
        bf16x8 ah = *(const bf16x8*)&Ah[(wave * 16 + l16) * LDA1 + j0];
        bf16x8 al = *(const bf16x8*)&Al[(wave * 16 + l16) * LDA1 + j0];
#pragma unroll
        for (int t = 0; t < 4; t++) {
            bf16x8 bh = *(const bf16x8*)&Xh[(t * 16 + l16) * LDA1 + j0];
            bf16x8 bl = *(const bf16x8*)&Xl[(t * 16 + l16) * LDA1 + j0];
            acc[t] = __builtin_amdgcn_mfma_f32_16x16x32_bf16(ah, bh, acc[t], 0, 0, 0);
            acc[t] = __builtin_amdgcn_mfma_f32_16x16x32_bf16(ah, bl, acc[t], 0, 0, 0);
            acc[t] = __builtin_amdgcn_mfma_f32_16x16x32_bf16(al, bh, acc[t], 0, 0, 0);
        }
    }
    // epilogue1: x1 = relu(acc + (Pa-Qa) + b1); write bf16 global + Tt LDS
#pragma unroll
    for (int t = 0; t < 4; t++) {
        int cl = t * 16 + l16;      // local col
        int c = w0 + cl;            // global col (< 512)
        float bb = bias[c];
        float qa = Q[c];
#pragma unroll
        for (int r = 0; r < 4; r++) {
            int k = wave * 16 + quad * 4 + r;
            float ua = P[(size_t)rowid[k] * 1024 + c] - qa;
            float v = fmaxf(acc[t][r] + ua + bb, 0.f);
            unsigned short hv = f2bf(v);
            xout[(size_t)k * 1024 + c] = hv;
            Tt[cl * LDA1 + k] = hv;
        }
    }
    __syncthreads();
    // mix2: acc2 = A @ bf16(x1) (2-pass hi/lo on A)
    f32x4 acc2[4];
#pragma unroll
    for (int t = 0; t < 4; t++) acc2[t] = (f32x4){0.f, 0.f, 0.f, 0.f};
#pragma unroll
    for (int ks = 0; ks < 2; ks++) {
        int j0 = ks * 32 + quad * 8;
        bf16x8 ah = *(const bf16x8*)&Ah[(wave * 16 + l16) * LDA1 + j0];
        bf16x8 al = *(const bf16x8*)&Al[(wave * 16 + l16) * LDA1 + j0];
#pragma unroll
        for (int t = 0; t < 4; t++) {
            bf16x8 bh = *(const bf16x8*)&Tt[(t * 16 + l16) * LDA1 + j0];
            acc2[t] = __builtin_amdgcn_mfma_f32_16x16x32_bf16(ah, bh, acc2[t], 0, 0, 0);
            acc2[t] = __builtin_amdgcn_mfma_f32_16x16x32_bf16(al, bh, acc2[t], 0, 0, 0);
        }
    }
    // epilogue2: y1 -> xy1 upper half
#pragma unroll
    for (int t = 0; t < 4; t++) {
        int c = 512 + w0 + t * 16 + l16;
#pragma unroll
        for (int r = 0; r < 4; r++) {
            int k = wave * 16 + quad * 4 + r;
            xout[(size_t)k * 1024 + c] = f2bf(acc2[t][r]);
        }
    }
}

// ---------------- 2-class softmax from accumulated logits ----------------
__global__ void k_soft2(const float* __restrict__ lbuf, const float* __restrict__ bc2,
                        float* __restrict__ pred) {
    int m = blockIdx.x * 256 + threadIdx.x;
    if (m < Bq * Kn) {
        float L0 = lbuf[2 * m] + bc2[0];
        float L1 = lbuf[2 * m + 1] + bc2[1];
        float mx = fmaxf(L0, L1);
        float e0 = expf(L0 - mx), e1 = expf(L1 - mx);
        float inv = 1.f / (e0 + e1);
        pred[2 * m] = e0 * inv;
        pred[2 * m + 1] = e1 * inv;
    }
}

// ---------------- launch ----------------
extern "C" void kernel_launch(void* const* d_in, const int* in_sizes, int n_in,
                              void* d_out, int out_size, void* d_ws, size_t ws_size,
                              hipStream_t stream) {
    const int* indexes = (const int*)d_in[0];
    const float* features = (const float*)d_in[1];
    const int* labels = (const int*)d_in[2];
    const int* knn = (const int*)d_in[5];
    const float* all_pred = (const float*)d_in[6];
    const float* W1 = (const float*)d_in[7];
    const float* b1 = (const float*)d_in[8];
    const float* W2 = (const float*)d_in[9];
    const float* b2 = (const float*)d_in[10];
    const float* Wc1 = (const float*)d_in[11];
    const float* bc1 = (const float*)d_in[12];
    const float* pre_a = (const float*)d_in[13];
    const float* Wc2 = (const float*)d_in[14];
    const float* bc2 = (const float*)d_in[15];
    float* out = (float*)d_out;

    char* w = (char*)d_ws;
    size_t o = 0;
    auto carve = [&](size_t bytes) -> char* {
        char* p = w + o;
        o += (bytes + 255) & ~(size_t)255;
        return p;
    };
    int* cnt = (int*)carve((size_t)Cc * 4);
    int* off = (int*)carve((size_t)Cc * 4);
    int* pos = (int*)carve((size_t)Cc * 4);
    int* total = (int*)carve(4);
    int* rowidx = (int*)carve((size_t)Nn * 4);
    float* clu_mean = (float*)carve((size_t)Cc * Dd * 4);                       // 41 MB
    unsigned short* PA = (unsigned short*)carve((size_t)MP * Dd * 2);           // 22 MB
    float* Pout = (float*)carve((size_t)MP * 2 * NHID * 4);                     // 22 MB
    float* Abuf = (float*)carve((size_t)Bq * Kn * Kn * 4);                      // 4.2 MB
    unsigned short* Bp1 = (unsigned short*)carve((size_t)(Dd / 8) * 1024 * 8 * 2);   // 4.2 MB
    unsigned short* xy1 = (unsigned short*)carve((size_t)Bq * Kn * 1024 * 2);   // 33.6 MB
    unsigned short* Bp2 = (unsigned short*)carve((size_t)(2 * NHID / 8) * H2d * 8 * 2);  // 0.52 MB
    unsigned short* x2 = (unsigned short*)carve((size_t)Bq * Kn * H2d * 2);     // 8.4 MB
    unsigned short* Bpc = (unsigned short*)carve((size_t)(H2d / 8) * 256 * 8 * 2);   // 0.13 MB
    float* lbuf = (float*)carve((size_t)Bq * Kn * 2 * 4);                       // 0.13 MB

    float* simm_out = out + (size_t)Bq * Kn * 2;

    // 1) zero: cnt, PA pad rows, lbuf, alloc counter  (one kernel)
    {
        int nPad = (PIVROW - Cc) * Dd / 2;   // pad shorts -> ints
        int nLb = Bq * Kn * 2;               // floats -> ints (0 bits == 0.0f)
        int ntot = Cc + nPad + nLb + 1;
        k_zero_multi<<<(ntot + 255) / 256, 256, 0, stream>>>(
            cnt, Cc, (int*)(PA + (size_t)Cc * Dd), nPad, (int*)lbuf, nLb, total, 1);
    }
    k_count<<<(Nn + 255) / 256, 256, 0, stream>>>(labels, cnt, Nn);
    k_alloc<<<(Cc + 255) / 256, 256, 0, stream>>>(cnt, off, pos, total, Cc);
    k_scatter<<<(Nn + 255) / 256, 256, 0, stream>>>(labels, pos, rowidx, Nn);

    // 2) cluster means + simm + normalized means; pivot rows appended to grid
    k_meansimm<<<Cc + Bq, 256, 0, stream>>>(features, rowidx, off, cnt, indexes,
                                            clu_mean, simm_out, PA);

    // 3) per-batch adjacency (MFMA hi/lo gram), 512 threads
    k_build_ax<<<Bq, 512, 0, stream>>>(features, clu_mean, labels, indexes, knn,
                                       all_pred, Abuf);

    // 3b) all weight packs in one launch
    k_pack_all<<<1184, 256, 0, stream>>>(W1, W2, Wc1, Bp1, Bp2, Bpc);

    // 4) Pout = PA @ [W1a | W1b]  (M=5376, K=2048, N=1024), BM=64 -> 672 blocks
    {
        dim3 g(1024 / 128, MP / 64);
        gemm_bf16_mfma<64, 0><<<g, 256, 0, stream>>>(PA, Bp1, Pout, MP, Dd, 1024,
                                                     nullptr, nullptr, nullptr, nullptr);
    }
    // 5) fused layer-1: x1 + y1 -> xy1 (MFMA), one window per block
    {
        dim3 g(Bq, 8);
        k_gcn1<<<g, 256, 0, stream>>>(Pout, Abuf, labels, knn, b1, xy1);
    }
    // 6) x2 = relu([x1|y1] @ W2 + b2)  (M=16384, K=1024, N=256), BM=64 -> 512 blocks
    {
        dim3 g(H2d / 128, (Bq * Kn) / 64);
        gemm_bf16_mfma<64, 2><<<g, 256, 0, stream>>>(xy1, Bp2, x2, Bq * Kn, 1024, H2d,
                                                     b2, nullptr, nullptr, nullptr);
    }
    // 7) logits = prelu(x2 @ Wc1 + bc1) @ Wc2 -> lbuf, BM=64 -> 512 blocks
    {
        dim3 g(H2d / 128, (Bq * Kn) / 64);
        gemm_bf16_mfma<64, 3><<<g, 256, 0, stream>>>(x2, Bpc, nullptr, Bq * Kn, H2d, H2d,
                                                     bc1, pre_a, Wc2, lbuf);
    }
    // 8) softmax -> pred
    k_soft2<<<(Bq * Kn + 255) / 256, 256, 0, stream>>>(lbuf, bc2, out);

    (void)in_sizes; (void)n_in; (void)out_size; (void)ws_size;
}

// Round 5
// 756.425 us; speedup vs baseline: 1.1986x; 1.0080x over previous
//
#include <hip/hip_runtime.h>
#include <math.h>

#define Bq 256
#define Kn 64
#define Dd 2048
#define Nn 50000
#define Cc 5000
#define NHID 512
#define H2d 256
#define LDH 264   // padded LDS row stride (shorts) for gram staging
#define MP 5376   // padded P-matrix rows: 5000 cn + 120 pad + 256 pivots
#define PIVROW 5120
#define LDA1 72   // LDS row stride (shorts) for gcn1 tiles
#define LDX 264   // LDS row stride (shorts) for gemm23 x2 tile

typedef __attribute__((ext_vector_type(8))) __bf16 bf16x8;
typedef __attribute__((ext_vector_type(4))) float f32x4;

__device__ __forceinline__ unsigned short f2bf(float f) {
    union { float f; unsigned int u; } v;
    v.f = f;
    unsigned int u = v.u;
    unsigned int r = (u + 0x7fff + ((u >> 16) & 1)) >> 16;   // RNE
    return (unsigned short)r;
}
__device__ __forceinline__ float bf2f(unsigned short h) {
    union { unsigned int u; float f; } v;
    v.u = ((unsigned int)h) << 16;
    return v.f;
}
__device__ __forceinline__ unsigned int hl_pack(float f) {
    unsigned short h = f2bf(f);
    unsigned short l = f2bf(f - bf2f(h));
    return (unsigned int)h | ((unsigned int)l << 16);
}

// ---------------- merged zero kernel ----------------
__global__ void k_zero_multi(int* __restrict__ p0, int n0,
                             int* __restrict__ p1, int n1,
                             int* __restrict__ p2, int n2,
                             int* __restrict__ p3, int n3) {
    int i = blockIdx.x * 256 + threadIdx.x;
    if (i < n0) { p0[i] = 0; return; }
    i -= n0;
    if (i < n1) { p1[i] = 0; return; }
    i -= n1;
    if (i < n2) { p2[i] = 0; return; }
    i -= n2;
    if (i < n3) p3[i] = 0;
}

__global__ void k_count(const int* __restrict__ labels, int* __restrict__ cnt, int n) {
    int i = blockIdx.x * 256 + threadIdx.x;
    if (i < n) atomicAdd(&cnt[labels[i]], 1);
}

// atomic segment allocator: contiguous (unordered) cluster offsets
__global__ void k_alloc(const int* __restrict__ cnt, int* __restrict__ off,
                        int* __restrict__ pos, int* __restrict__ total, int C) {
    int c = blockIdx.x * 256 + threadIdx.x;
    if (c < C) {
        int o = atomicAdd(total, cnt[c]);
        off[c] = o;
        pos[c] = o;
    }
}

__global__ void k_scatter(const int* __restrict__ labels, int* __restrict__ pos,
                          int* __restrict__ rowidx, int n) {
    int i = blockIdx.x * 256 + threadIdx.x;
    if (i < n) {
        int p = atomicAdd(&pos[labels[i]], 1);
        rowidx[p] = i;
    }
}

// ---------------- cluster mean + simm + normalized-mean (bf16) + hi/lo pack ----------------
__global__ __launch_bounds__(256) void k_meansimm(
    const float* __restrict__ feat, const int* __restrict__ rowidx,
    const int* __restrict__ off, const int* __restrict__ cnt,
    const int* __restrict__ indexes,
    unsigned int* __restrict__ HLm, unsigned int* __restrict__ HLp,
    float* __restrict__ simm, unsigned short* __restrict__ PA) {
    int c = blockIdx.x;
    int t = threadIdx.x;
    __shared__ float red[256];

    if (c >= Cc) {
        // pivot path: raw feature row -> HLp (hi/lo pack) + normalized -> PA[PIVROW+b]
        int b = c - Cc;
        const float* row = feat + (size_t)indexes[b] * Dd;
        float4 v0 = *(const float4*)(row + t * 4);
        float4 v1 = *(const float4*)(row + 1024 + t * 4);
        uint4 u0, u1;
        u0.x = hl_pack(v0.x); u0.y = hl_pack(v0.y); u0.z = hl_pack(v0.z); u0.w = hl_pack(v0.w);
        u1.x = hl_pack(v1.x); u1.y = hl_pack(v1.y); u1.z = hl_pack(v1.z); u1.w = hl_pack(v1.w);
        unsigned int* hp = HLp + (size_t)b * Dd;
        *(uint4*)(hp + t * 4) = u0;
        *(uint4*)(hp + 1024 + t * 4) = u1;
        float ss = v0.x * v0.x + v0.y * v0.y + v0.z * v0.z + v0.w * v0.w +
                   v1.x * v1.x + v1.y * v1.y + v1.z * v1.z + v1.w * v1.w;
        red[t] = ss;
        __syncthreads();
        for (int s2 = 128; s2 > 0; s2 >>= 1) {
            if (t < s2) red[t] += red[t + s2];
            __syncthreads();
        }
        float tot = red[0];
        float rnn = (tot > 0.f) ? rsqrtf(tot) : 0.f;
        ushort4 c0, c1;
        c0.x = f2bf(v0.x * rnn); c0.y = f2bf(v0.y * rnn);
        c0.z = f2bf(v0.z * rnn); c0.w = f2bf(v0.w * rnn);
        c1.x = f2bf(v1.x * rnn); c1.y = f2bf(v1.y * rnn);
        c1.z = f2bf(v1.z * rnn); c1.w = f2bf(v1.w * rnn);
        unsigned short* cr = PA + (size_t)(PIVROW + b) * Dd;
        *(ushort4*)(cr + t * 4) = c0;
        *(ushort4*)(cr + 1024 + t * 4) = c1;
        return;
    }

    int n = cnt[c], st = off[c];
    float4 a0 = {0.f, 0.f, 0.f, 0.f}, a1 = {0.f, 0.f, 0.f, 0.f};
    for (int r = 0; r < n; r++) {
        const float* row = feat + (size_t)rowidx[st + r] * Dd;
        float4 v0 = *(const float4*)(row + t * 4);
        float4 v1 = *(const float4*)(row + 1024 + t * 4);
        a0.x += v0.x; a0.y += v0.y; a0.z += v0.z; a0.w += v0.w;
        a1.x += v1.x; a1.y += v1.y; a1.z += v1.z; a1.w += v1.w;
    }
    float sc = 1.f / (float)(n > 1 ? n : 1);
    a0.x *= sc; a0.y *= sc; a0.z *= sc; a0.w *= sc;
    a1.x *= sc; a1.y *= sc; a1.z *= sc; a1.w *= sc;
    // hi/lo pack of the f32 mean (exact values build_ax previously derived)
    uint4 u0, u1;
    u0.x = hl_pack(a0.x); u0.y = hl_pack(a0.y); u0.z = hl_pack(a0.z); u0.w = hl_pack(a0.w);
    u1.x = hl_pack(a1.x); u1.y = hl_pack(a1.y); u1.z = hl_pack(a1.z); u1.w = hl_pack(a1.w);
    unsigned int* hm = HLm + (size_t)c * Dd;
    *(uint4*)(hm + t * 4) = u0;
    *(uint4*)(hm + 1024 + t * 4) = u1;
    float ss = a0.x * a0.x + a0.y * a0.y + a0.z * a0.z + a0.w * a0.w +
               a1.x * a1.x + a1.y * a1.y + a1.z * a1.z + a1.w * a1.w;
    red[t] = ss;
    __syncthreads();
    for (int s2 = 128; s2 > 0; s2 >>= 1) {
        if (t < s2) red[t] += red[t + s2];
        __syncthreads();
    }
    if (t == 0) simm[c] = red[0];
    float tot = red[0];
    float rnn = (tot > 0.f) ? rsqrtf(tot) : 0.f;
    ushort4 c0, c1;
    c0.x = f2bf(a0.x * rnn); c0.y = f2bf(a0.y * rnn);
    c0.z = f2bf(a0.z * rnn); c0.w = f2bf(a0.w * rnn);
    c1.x = f2bf(a1.x * rnn); c1.y = f2bf(a1.y * rnn);
    c1.z = f2bf(a1.z * rnn); c1.w = f2bf(a1.w * rnn);
    unsigned short* cr = PA + (size_t)c * Dd;
    *(ushort4*)(cr + t * 4) = c0;
    *(ushort4*)(cr + 1024 + t * 4) = c1;
}

// ---------------- per-batch: A (MFMA hi/lo gram), 1024 threads, pre-split input ----------------
__global__ __launch_bounds__(1024) void k_build_ax(
    const unsigned int* __restrict__ HLm, const unsigned int* __restrict__ HLp,
    const int* __restrict__ labels, const int* __restrict__ knn,
    const float* __restrict__ all_pred, float* __restrict__ Abuf) {
    __shared__ unsigned short Hs[64 * LDH];
    __shared__ unsigned short Ls[64 * LDH];
    __shared__ float Gs[64 * 65];
    __shared__ const unsigned int* rowp[64];
    __shared__ float wj64[64];

    int b = blockIdx.x, tid = threadIdx.x;
    int wave = tid >> 6, lane = tid & 63, quad = lane >> 4, l16 = lane & 15;
    int rs = (wave >> 2) * 16;   // row strip (4 groups)
    int ct = wave & 3;           // col tile (4)

    if (tid < 64) {
        const unsigned int* p = (tid == 0) ? HLp + (size_t)b * Dd
                                           : HLm + (size_t)labels[knn[b * 64 + tid]] * Dd;
        rowp[tid] = p;
        wj64[tid] = expf(all_pred[(b * 64 + tid) * 2 + 1]);
    }
    __syncthreads();

    f32x4 acc = (f32x4){0.f, 0.f, 0.f, 0.f};

    for (int ch = 0; ch < 8; ch++) {
        int d0 = ch * 256;
        __syncthreads();   // protect Hs/Ls from previous chunk's readers
#pragma unroll
        for (int q = 0; q < 4; q++) {
            int e4 = tid + q * 1024;
            int row = e4 >> 6;
            int c4 = (e4 & 63) * 4;
            uint4 u = *(const uint4*)(rowp[row] + d0 + c4);
            ushort4 h, l;
            h.x = (unsigned short)(u.x & 0xffff); l.x = (unsigned short)(u.x >> 16);
            h.y = (unsigned short)(u.y & 0xffff); l.y = (unsigned short)(u.y >> 16);
            h.z = (unsigned short)(u.z & 0xffff); l.z = (unsigned short)(u.z >> 16);
            h.w = (unsigned short)(u.w & 0xffff); l.w = (unsigned short)(u.w >> 16);
            *(ushort4*)&Hs[row * LDH + c4] = h;
            *(ushort4*)&Ls[row * LDH + c4] = l;
        }
        __syncthreads();
#pragma unroll
        for (int ks = 0; ks < 8; ks++) {
            int kk = ks * 32 + quad * 8;
            bf16x8 ah = *(const bf16x8*)&Hs[(rs + l16) * LDH + kk];
            bf16x8 al = *(const bf16x8*)&Ls[(rs + l16) * LDH + kk];
            bf16x8 bh = *(const bf16x8*)&Hs[(ct * 16 + l16) * LDH + kk];
            bf16x8 bl = *(const bf16x8*)&Ls[(ct * 16 + l16) * LDH + kk];
            acc = __builtin_amdgcn_mfma_f32_16x16x32_bf16(ah, bh, acc, 0, 0, 0);
            acc = __builtin_amdgcn_mfma_f32_16x16x32_bf16(ah, bl, acc, 0, 0, 0);
            acc = __builtin_amdgcn_mfma_f32_16x16x32_bf16(al, bh, acc, 0, 0, 0);
        }
    }
    __syncthreads();
#pragma unroll
    for (int r = 0; r < 4; r++)
        Gs[(rs + quad * 4 + r) * 65 + ct * 16 + l16] = acc[r];
    __syncthreads();
    // parallel row softmax: 64 rows x 16 lanes, 4 cols per lane
    {
        int r = tid >> 4, s = tid & 15;
        float e[4];
        float mx = -1e30f;
#pragma unroll
        for (int c8 = 0; c8 < 4; c8++) {
            int c = s * 4 + c8;
            float v = Gs[r * 65 + c] * wj64[c];
            e[c8] = v;
            mx = fmaxf(mx, v);
        }
        mx = fmaxf(mx, __shfl_xor(mx, 1, 64));
        mx = fmaxf(mx, __shfl_xor(mx, 2, 64));
        mx = fmaxf(mx, __shfl_xor(mx, 4, 64));
        mx = fmaxf(mx, __shfl_xor(mx, 8, 64));
        float sum = 0.f;
#pragma unroll
        for (int c8 = 0; c8 < 4; c8++) {
            e[c8] = expf(e[c8] - mx);
            sum += e[c8];
        }
        sum += __shfl_xor(sum, 1, 64);
        sum += __shfl_xor(sum, 2, 64);
        sum += __shfl_xor(sum, 4, 64);
        sum += __shfl_xor(sum, 8, 64);
        float inv = 1.f / sum;
        float* Arow = Abuf + ((size_t)b * 64 + r) * 64;
#pragma unroll
        for (int c8 = 0; c8 < 4; c8++) Arow[s * 4 + c8] = e[c8] * inv;
    }
}

// ---------------- merged weight repack ----------------
__device__ __forceinline__ void pack_item(const float* __restrict__ W,
                                          unsigned short* __restrict__ Bp,
                                          int K, int Nhalf, int split, int idx) {
    int Ntot = split ? 2 * Nhalf : Nhalf;
    int kb = idx / Ntot;
    int n = idx - kb * Ntot;
    float v[8];
#pragma unroll
    for (int j = 0; j < 8; j++) {
        int k = kb * 8 + j;
        if (split)
            v[j] = (n < Nhalf) ? W[(size_t)k * Nhalf + n]
                               : W[(size_t)(K + k) * Nhalf + (n - Nhalf)];
        else
            v[j] = W[(size_t)k * Nhalf + n];
    }
    ushort4 lo, hi;
    lo.x = f2bf(v[0]); lo.y = f2bf(v[1]); lo.z = f2bf(v[2]); lo.w = f2bf(v[3]);
    hi.x = f2bf(v[4]); hi.y = f2bf(v[5]); hi.z = f2bf(v[6]); hi.w = f2bf(v[7]);
    *(ushort4*)&Bp[(size_t)idx * 8] = lo;
    *(ushort4*)&Bp[(size_t)idx * 8 + 4] = hi;
}

// blocks [0,1024): W1 split-pack; [1024,1152): W2 straight (K=1024); [1152,1184): Wc1
__global__ __launch_bounds__(256) void k_pack_all(
    const float* __restrict__ W1, const float* __restrict__ W2,
    const float* __restrict__ Wc1, unsigned short* __restrict__ Bp1,
    unsigned short* __restrict__ Bp2, unsigned short* __restrict__ Bpc) {
    int blk = blockIdx.x;
    int tid = threadIdx.x;
    if (blk < 1024) {
        pack_item(W1, Bp1, Dd, NHID, 1, blk * 256 + tid);
    } else if (blk < 1024 + 128) {
        pack_item(W2, Bp2, 2 * NHID, H2d, 0, (blk - 1024) * 256 + tid);
    } else {
        pack_item(Wc1, Bpc, H2d, H2d, 0, (blk - 1152) * 256 + tid);
    }
}

// ---------------- bf16 MFMA GEMM, BM=64 (used for GEMM1 only now) ----------------
__global__ __launch_bounds__(256) void gemm_bf16_mfma(
    const unsigned short* __restrict__ A, const unsigned short* __restrict__ Bp,
    float* __restrict__ C, int M, int K, int N) {
    __shared__ unsigned short Asm[64 * 32];
    __shared__ unsigned short Bsm[4 * 128 * 8];
    int tid = threadIdx.x;
    int wave = tid >> 6, lane = tid & 63;
    int quad = lane >> 4, l16 = lane & 15;
    int m0 = blockIdx.y * 64, n0 = blockIdx.x * 128;
    int wm = (wave >> 1) * 32, wn = (wave & 1) * 64;

    f32x4 acc[2][4];
#pragma unroll
    for (int i = 0; i < 2; i++)
#pragma unroll
        for (int j = 0; j < 4; j++) acc[i][j] = (f32x4){0.f, 0.f, 0.f, 0.f};

    const unsigned short* gA0 = A + (size_t)(m0 + wave * 16 + (lane >> 2)) * K + (lane & 3) * 8;
    const unsigned short* gB0 = Bp + (size_t)(n0 + lane) * 8 + (size_t)wave * N * 8;

    for (int k0 = 0; k0 < K; k0 += 32) {
        __syncthreads();
        size_t bko = (size_t)(k0 >> 3) * N * 8;
        __builtin_amdgcn_global_load_lds(
            (const __attribute__((address_space(1))) void*)(gA0 + k0),
            (__attribute__((address_space(3))) void*)(Asm + wave * 512), 16, 0, 0);
        __builtin_amdgcn_global_load_lds(
            (const __attribute__((address_space(1))) void*)(gB0 + bko),
            (__attribute__((address_space(3))) void*)(Bsm + wave * 1024), 16, 0, 0);
        __builtin_amdgcn_global_load_lds(
            (const __attribute__((address_space(1))) void*)(gB0 + bko + 512),
            (__attribute__((address_space(3))) void*)(Bsm + wave * 1024 + 512), 16, 0, 0);
        __syncthreads();

        bf16x8 a[2], b[4];
#pragma unroll
        for (int i = 0; i < 2; i++)
            a[i] = *(const bf16x8*)&Asm[(wm + i * 16 + l16) * 32 + quad * 8];
#pragma unroll
        for (int j = 0; j < 4; j++)
            b[j] = *(const bf16x8*)&Bsm[quad * 1024 + (wn + j * 16 + l16) * 8];
#pragma unroll
        for (int i = 0; i < 2; i++)
#pragma unroll
            for (int j = 0; j < 4; j++)
                acc[i][j] = __builtin_amdgcn_mfma_f32_16x16x32_bf16(
                    a[i], b[j], acc[i][j], 0, 0, 0);
    }

#pragma unroll
    for (int i = 0; i < 2; i++)
#pragma unroll
        for (int j = 0; j < 4; j++) {
            int col = n0 + wn + j * 16 + l16;
#pragma unroll
            for (int r = 0; r < 4; r++) {
                int row = m0 + wm + i * 16 + quad * 4 + r;
                C[(size_t)row * N + col] = acc[i][j][r];
            }
        }
}

// ---------------- fused GEMM2+GEMM3: x2 tile in LDS, logits out ----------------
// grid 256 blocks: block owns 64 rows. Stage1: x2 = relu(xy1@W2 + b2) -> bf16 LDS.
// Stage2: prelu(x2@Wc1 + bc1) dot Wc2 -> atomicAdd lbuf.
__global__ __launch_bounds__(256) void k_gemm23(
    const unsigned short* __restrict__ A, const unsigned short* __restrict__ Bp2,
    const unsigned short* __restrict__ Bpc, const float* __restrict__ b2,
    const float* __restrict__ bc1, const float* __restrict__ pre_a,
    const float* __restrict__ wc2, float* __restrict__ lbuf) {
    __shared__ unsigned short Asm[64 * 32];        // 4 KB
    __shared__ unsigned short Bsm[4 * 256 * 8];    // 16 KB
    __shared__ unsigned short Xs[64 * LDX];        // 33 KB x2 tile
    int tid = threadIdx.x;
    int wave = tid >> 6, lane = tid & 63;
    int quad = lane >> 4, l16 = lane & 15;
    int m0 = blockIdx.x * 64;
    int wn = wave * 64;   // output col strip per wave

    f32x4 acc[4][4];
#pragma unroll
    for (int i = 0; i < 4; i++)
#pragma unroll
        for (int j = 0; j < 4; j++) acc[i][j] = (f32x4){0.f, 0.f, 0.f, 0.f};

    const unsigned short* gA0 = A + (size_t)(m0 + wave * 16 + (lane >> 2)) * 1024 + (lane & 3) * 8;

    // ---- stage 1: K=1024 over xy1, N=256 ----
    for (int k0 = 0; k0 < 1024; k0 += 32) {
        __syncthreads();
        __builtin_amdgcn_global_load_lds(
            (const __attribute__((address_space(1))) void*)(gA0 + k0),
            (__attribute__((address_space(3))) void*)(Asm + wave * 512), 16, 0, 0);
        const unsigned short* gB = Bp2 + ((size_t)((k0 >> 3) + wave)) * 256 * 8;
#pragma unroll
        for (int q = 0; q < 4; q++) {
            __builtin_amdgcn_global_load_lds(
                (const __attribute__((address_space(1))) void*)(gB + (q * 64 + lane) * 8),
                (__attribute__((address_space(3))) void*)(Bsm + wave * 2048 + q * 512),
                16, 0, 0);
        }
        __syncthreads();
        bf16x8 a[4], b[4];
#pragma unroll
        for (int i = 0; i < 4; i++)
            a[i] = *(const bf16x8*)&Asm[(i * 16 + l16) * 32 + quad * 8];
#pragma unroll
        for (int j = 0; j < 4; j++)
            b[j] = *(const bf16x8*)&Bsm[quad * 2048 + (wn + j * 16 + l16) * 8];
#pragma unroll
        for (int i = 0; i < 4; i++)
#pragma unroll
            for (int j = 0; j < 4; j++)
                acc[i][j] = __builtin_amdgcn_mfma_f32_16x16x32_bf16(
                    a[i], b[j], acc[i][j], 0, 0, 0);
    }
    __syncthreads();   // all stage-1 LDS reads done
    // epilogue 1: relu + bias -> bf16 into Xs
#pragma unroll
    for (int i = 0; i < 4; i++)
#pragma unroll
        for (int j = 0; j < 4; j++) {
            int col = wn + j * 16 + l16;
            float bcol = b2[col];
#pragma unroll
            for (int r = 0; r < 4; r++) {
                int row = i * 16 + quad * 4 + r;
                float v = fmaxf(acc[i][j][r] + bcol, 0.f);
                Xs[row * LDX + col] = f2bf(v);
            }
        }

    // ---- stage 2: K=256 over Xs, N=256 ----
    f32x4 acc2[4][4];
#pragma unroll
    for (int i = 0; i < 4; i++)
#pragma unroll
        for (int j = 0; j < 4; j++) acc2[i][j] = (f32x4){0.f, 0.f, 0.f, 0.f};

    for (int k0 = 0; k0 < 256; k0 += 32) {
        __syncthreads();   // Xs ready (iter 0) / Bsm free (later iters)
        const unsigned short* gB = Bpc + ((size_t)((k0 >> 3) + wave)) * 256 * 8;
#pragma unroll
        for (int q = 0; q < 4; q++) {
            __builtin_amdgcn_global_load_lds(
                (const __attribute__((address_space(1))) void*)(gB + (q * 64 + lane) * 8),
                (__attribute__((address_space(3))) void*)(Bsm + wave * 2048 + q * 512),
                16, 0, 0);
        }
        __syncthreads();
        bf16x8 a[4], b[4];
#pragma unroll
        for (int i = 0; i < 4; i++)
            a[i] = *(const bf16x8*)&Xs[(i * 16 + l16) * LDX + k0 + quad * 8];
#pragma unroll
        for (int j = 0; j < 4; j++)
            b[j] = *(const bf16x8*)&Bsm[quad * 2048 + (wn + j * 16 + l16) * 8];
#pragma unroll
        for (int i = 0; i < 4; i++)
#pragma unroll
            for (int j = 0; j < 4; j++)
                acc2[i][j] = __builtin_amdgcn_mfma_f32_16x16x32_bf16(
                    a[i], b[j], acc2[i][j], 0, 0, 0);
    }
    // epilogue 2: prelu + logit dot, reduce over l16, atomicAdd
#pragma unroll
    for (int i = 0; i < 4; i++) {
#pragma unroll
        for (int r = 0; r < 4; r++) {
            float l0 = 0.f, l1 = 0.f;
#pragma unroll
            for (int j = 0; j < 4; j++) {
                int col = wn + j * 16 + l16;
                float v = acc2[i][j][r] + bc1[col];
                v = (v >= 0.f) ? v : pre_a[col] * v;
                l0 += v * wc2[2 * col];
                l1 += v * wc2[2 * col + 1];
            }
#pragma unroll
            for (int mm = 1; mm < 16; mm <<= 1) {
                l0 += __shfl_xor(l0, mm, 64);
                l1 += __shfl_xor(l1, mm, 64);
            }
            if (l16 == 0) {
                int row = m0 + i * 16 + quad * 4 + r;
                atomicAdd(&lbuf[2 * row], l0);
                atomicAdd(&lbuf[2 * row + 1], l1);
            }
        }
    }
}

// ---------------- fused layer-1: x1 = relu((Pa-Qa) + A@(Pb-Qb) + b1), y1 = A@x1 ----------------
// grid (Bq, 8): block (b, w) handles col window w of 8. Windows are independent.
__global__ __launch_bounds__(256) void k_gcn1(
    const float* __restrict__ P, const float* __restrict__ Abuf,
    const int* __restrict__ labels, const int* __restrict__ knn,
    const float* __restrict__ bias, unsigned short* __restrict__ xy1) {
    __shared__ unsigned short Ah[64 * LDA1], Al[64 * LDA1];   // adjacency hi/lo [k'][j]
    __shared__ unsigned short Xh[64 * LDA1], Xl[64 * LDA1];   // D transposed [c][j]
    __shared__ unsigned short Tt[64 * LDA1];                  // x1 tile transposed [c][k]
    __shared__ int rowid[64];

    int b = blockIdx.x, w = blockIdx.y, tid = threadIdx.x;
    int wave = tid >> 6, lane = tid & 63, quad = lane >> 4, l16 = lane & 15;
    int w0 = w * 64;

    if (tid < 64)
        rowid[tid] = (tid == 0) ? (PIVROW + b) : labels[knn[b * 64 + tid]];

    // stage adjacency hi/lo (row-major [k'][j])
    const float* Ab = Abuf + (size_t)b * 64 * 64;
#pragma unroll
    for (int q = 0; q < 4; q++) {
        int e4 = tid + q * 256;
        int row = e4 >> 4;
        int c4 = (e4 & 15) * 4;
        float4 v = *(const float4*)(Ab + row * 64 + c4);
        ushort4 h, l;
        h.x = f2bf(v.x); l.x = f2bf(v.x - bf2f(h.x));
        h.y = f2bf(v.y); l.y = f2bf(v.y - bf2f(h.y));
        h.z = f2bf(v.z); l.z = f2bf(v.z - bf2f(h.z));
        h.w = f2bf(v.w); l.w = f2bf(v.w - bf2f(h.w));
        *(ushort4*)&Ah[row * LDA1 + c4] = h;
        *(ushort4*)&Al[row * LDA1 + c4] = l;
    }

    const float* Q = P + (size_t)(PIVROW + b) * 1024;
    unsigned short* xout = xy1 + (size_t)b * 64 * 1024;

    // stage D[j][c] = Pb[rowid[j]][c] - Qb[c], transposed hi/lo (uses knn directly,
    // rowid[] not yet visible)
#pragma unroll
    for (int q = 0; q < 4; q++) {
        int e4 = tid + q * 256;
        int j = e4 >> 4;
        int c4 = (e4 & 15) * 4;
        int rid = (j == 0) ? (PIVROW + b) : labels[knn[b * 64 + j]];
        float4 v = *(const float4*)(P + (size_t)rid * 1024 + 512 + w0 + c4);
        float4 qv = *(const float4*)(Q + 512 + w0 + c4);
        v.x -= qv.x; v.y -= qv.y; v.z -= qv.z; v.w -= qv.w;
        unsigned short h;
        h = f2bf(v.x); Xh[(c4 + 0) * LDA1 + j] = h; Xl[(c4 + 0) * LDA1 + j] = f2bf(v.x - bf2f(h));
        h = f2bf(v.y); Xh[(c4 + 1) * LDA1 + j] = h; Xl[(c4 + 1) * LDA1 + j] = f2bf(v.y - bf2f(h));
        h = f2bf(v.z); Xh[(c4 + 2) * LDA1 + j] = h; Xl[(c4 + 2) * LDA1 + j] = f2bf(v.z - bf2f(h));
        h = f2bf(v.w); Xh[(c4 + 3) * LDA1 + j] = h; Xl[(c4 + 3) * LDA1 + j] = f2bf(v.w - bf2f(h));
    }
    __syncthreads();

    // mix1: acc = A @ D (3-pass hi/lo)
    f32x4 acc[4];
#pragma unroll
    for (int t = 0; t < 4; t++) acc[t] = (f32x4){0.f, 0.f, 0.f, 0.f};
#pragma unroll
    for (int ks = 0; ks < 2; ks++) {
        int j0 = ks * 32 + quad * 8;
        bf16x8 ah = *(const bf16x8*)&Ah[(wave * 16 + l16) * LDA1 + j0];
        bf16x8 al = *(const bf16x8*)&Al[(wave * 16 + l16) * LDA1 + j0];
#pragma unroll
        for (int t = 0; t < 4; t++) {
            bf16x8 bh = *(const bf16x8*)&Xh[(t * 16 + l16) * LDA1 + j0];
            bf16x8 bl = *(const bf16x8*)&Xl[(t * 16 + l16) * LDA1 + j0];
            acc[t] = __builtin_amdgcn_mfma_f32_16x16x32_bf16(ah, bh, acc[t], 0, 0, 0);
            acc[t] = __builtin_amdgcn_mfma_f32_16x16x32_bf16(ah, bl, acc[t], 0, 0, 0);
            acc[t] = __builtin_amdgcn_mfma_f32_16x16x32_bf16(al, bh, acc[t], 0, 0, 0);
        }
    }
    // epilogue1: x1 = relu(acc + (Pa-Qa) + b1); write bf16 global + Tt LDS
#pragma unroll
    for (int t = 0; t < 4; t++) {
        int cl = t * 16 + l16;      // local col
        int c = w0 + cl;            // global col (< 512)
        float bb = bias[c];
        float qa = Q[c];
#pragma unroll
        for (int r = 0; r < 4; r++) {
            int k = wave * 16 + quad * 4 + r;
            float ua = P[(size_t)rowid[k] * 1024 + c] - qa;
            float v = fmaxf(acc[t][r] + ua + bb, 0.f);
            unsigned short hv = f2bf(v);
            xout[(size_t)k * 1024 + c] = hv;
            Tt[cl * LDA1 + k] = hv;
        }
    }
    __syncthreads();
    // mix2: acc2 = A @ bf16(x1) (2-pass hi/lo on A)
    f32x4 acc2[4];
#pragma unroll
    for (int t = 0; t < 4; t++) acc2[t] = (f32x4){0.f, 0.f, 0.f, 0.f};
#pragma unroll
    for (int ks = 0; ks < 2; ks++) {
        int j0 = ks * 32 + quad * 8;
        bf16x8 ah = *(const bf16x8*)&Ah[(wave * 16 + l16) * LDA1 + j0];
        bf16x8 al = *(const bf16x8*)&Al[(wave * 16 + l16) * LDA1 + j0];
#pragma unroll
        for (int t = 0; t < 4; t++) {
            bf16x8 bh = *(const bf16x8*)&Tt[(t * 16 + l16) * LDA1 + j0];
            acc2[t] = __builtin_amdgcn_mfma_f32_16x16x32_bf16(ah, bh, acc2[t], 0, 0, 0);
            acc2[t] = __builtin_amdgcn_mfma_f32_16x16x32_bf16(al, bh, acc2[t], 0, 0, 0);
        }
    }
    // epilogue2: y1 -> xy1 upper half
#pragma unroll
    for (int t = 0; t < 4; t++) {
        int c = 512 + w0 + t * 16 + l16;
#pragma unroll
        for (int r = 0; r < 4; r++) {
            int k = wave * 16 + quad * 4 + r;
            xout[(size_t)k * 1024 + c] = f2bf(acc2[t][r]);
        }
    }
}

// ---------------- 2-class softmax from accumulated logits ----------------
__global__ void k_soft2(const float* __restrict__ lbuf, const float* __restrict__ bc2,
                        float* __restrict__ pred) {
    int m = blockIdx.x * 256 + threadIdx.x;
    if (m < Bq * Kn) {
        float L0 = lbuf[2 * m] + bc2[0];
        float L1 = lbuf[2 * m + 1] + bc2[1];
        float mx = fmaxf(L0, L1);
        float e0 = expf(L0 - mx), e1 = expf(L1 - mx);
        float inv = 1.f / (e0 + e1);
        pred[2 * m] = e0 * inv;
        pred[2 * m + 1] = e1 * inv;
    }
}

// ---------------- launch ----------------
extern "C" void kernel_launch(void* const* d_in, const int* in_sizes, int n_in,
                              void* d_out, int out_size, void* d_ws, size_t ws_size,
                              hipStream_t stream) {
    const int* indexes = (const int*)d_in[0];
    const float* features = (const float*)d_in[1];
    const int* labels = (const int*)d_in[2];
    const int* knn = (const int*)d_in[5];
    const float* all_pred = (const float*)d_in[6];
    const float* W1 = (const float*)d_in[7];
    const float* b1 = (const float*)d_in[8];
    const float* W2 = (const float*)d_in[9];
    const float* b2 = (const float*)d_in[10];
    const float* Wc1 = (const float*)d_in[11];
    const float* bc1 = (const float*)d_in[12];
    const float* pre_a = (const float*)d_in[13];
    const float* Wc2 = (const float*)d_in[14];
    const float* bc2 = (const float*)d_in[15];
    float* out = (float*)d_out;

    char* w = (char*)d_ws;
    size_t o = 0;
    auto carve = [&](size_t bytes) -> char* {
        char* p = w + o;
        o += (bytes + 255) & ~(size_t)255;
        return p;
    };
    int* cnt = (int*)carve((size_t)Cc * 4);
    int* off = (int*)carve((size_t)Cc * 4);
    int* pos = (int*)carve((size_t)Cc * 4);
    int* total = (int*)carve(4);
    int* rowidx = (int*)carve((size_t)Nn * 4);
    unsigned int* HLm = (unsigned int*)carve((size_t)Cc * Dd * 4);              // 41 MB hi/lo packed means
    unsigned int* HLp = (unsigned int*)carve((size_t)Bq * Dd * 4);              // 2 MB hi/lo packed pivots
    unsigned short* PA = (unsigned short*)carve((size_t)MP * Dd * 2);           // 22 MB
    float* Pout = (float*)carve((size_t)MP * 2 * NHID * 4);                     // 22 MB
    float* Abuf = (float*)carve((size_t)Bq * Kn * Kn * 4);                      // 4.2 MB
    unsigned short* Bp1 = (unsigned short*)carve((size_t)(Dd / 8) * 1024 * 8 * 2);   // 4.2 MB
    unsigned short* xy1 = (unsigned short*)carve((size_t)Bq * Kn * 1024 * 2);   // 33.6 MB
    unsigned short* Bp2 = (unsigned short*)carve((size_t)(2 * NHID / 8) * H2d * 8 * 2);  // 0.52 MB
    unsigned short* Bpc = (unsigned short*)carve((size_t)(H2d / 8) * 256 * 8 * 2);   // 0.13 MB
    float* lbuf = (float*)carve((size_t)Bq * Kn * 2 * 4);                       // 0.13 MB

    float* simm_out = out + (size_t)Bq * Kn * 2;

    // 1) zero: cnt, PA pad rows, lbuf, alloc counter  (one kernel)
    {
        int nPad = (PIVROW - Cc) * Dd / 2;   // pad shorts -> ints
        int nLb = Bq * Kn * 2;               // floats -> ints (0 bits == 0.0f)
        int ntot = Cc + nPad + nLb + 1;
        k_zero_multi<<<(ntot + 255) / 256, 256, 0, stream>>>(
            cnt, Cc, (int*)(PA + (size_t)Cc * Dd), nPad, (int*)lbuf, nLb, total, 1);
    }
    k_count<<<(Nn + 255) / 256, 256, 0, stream>>>(labels, cnt, Nn);
    k_alloc<<<(Cc + 255) / 256, 256, 0, stream>>>(cnt, off, pos, total, Cc);
    k_scatter<<<(Nn + 255) / 256, 256, 0, stream>>>(labels, pos, rowidx, Nn);

    // 2) cluster means + simm + normalized means + hi/lo packs; pivots appended
    k_meansimm<<<Cc + Bq, 256, 0, stream>>>(features, rowidx, off, cnt, indexes,
                                            HLm, HLp, simm_out, PA);

    // 3) per-batch adjacency (MFMA hi/lo gram), 1024 threads, pre-split input
    k_build_ax<<<Bq, 1024, 0, stream>>>(HLm, HLp, labels, knn, all_pred, Abuf);

    // 3b) all weight packs in one launch
    k_pack_all<<<1184, 256, 0, stream>>>(W1, W2, Wc1, Bp1, Bp2, Bpc);

    // 4) Pout = PA @ [W1a | W1b]  (M=5376, K=2048, N=1024), BM=64 -> 672 blocks
    {
        dim3 g(1024 / 128, MP / 64);
        gemm_bf16_mfma<<<g, 256, 0, stream>>>(PA, Bp1, Pout, MP, Dd, 1024);
    }
    // 5) fused layer-1: x1 + y1 -> xy1 (MFMA), one window per block
    {
        dim3 g(Bq, 8);
        k_gcn1<<<g, 256, 0, stream>>>(Pout, Abuf, labels, knn, b1, xy1);
    }
    // 6+7) fused: x2 = relu(xy1@W2+b2) in LDS; logits = prelu(x2@Wc1+bc1)@Wc2 -> lbuf
    k_gemm23<<<Bq * Kn / 64, 256, 0, stream>>>(xy1, Bp2, Bpc, b2, bc1, pre_a, Wc2, lbuf);

    // 8) softmax -> pred
    k_soft2<<<(Bq * Kn + 255) / 256, 256, 0, stream>>>(lbuf, bc2, out);

    (void)in_sizes; (void)n_in; (void)out_size; (void)ws_size;
}